// Round 5
// baseline (451.859 us; speedup 1.0000x reference)
//
#include <hip/hip_runtime.h>
#include <hip/hip_bf16.h>

#define N_NODES 50000
#define N_EDGES 800000
#define FDIM 128
#define CDIM 64
#define NGRAPH 256
#define LRELU_SLOPE 0.2f
#define SCAN_NB ((N_NODES + 1023) / 1024)   // 49
#define NE_PAD_MAX 1000000                   // padded CSR capacity (>= 800K + 3*50K)
#define NEG_INF_SCORE -1e30f

typedef unsigned short ushort_t;
typedef unsigned int uint_t;
typedef __attribute__((ext_vector_type(8))) short short8v;
typedef __attribute__((ext_vector_type(4))) float float4v;

// ---------------------------------------------------------------- bf16 helpers (RNE)
__device__ __forceinline__ ushort_t f2bf(float f) {
    uint_t u = __float_as_uint(f);
    u += 0x7FFFu + ((u >> 16) & 1u);
    return (ushort_t)(u >> 16);
}
__device__ __forceinline__ float bf2f(ushort_t u) {
    return __uint_as_float(((uint_t)u) << 16);
}

__device__ __forceinline__ float wave_sum(float v) {
#pragma unroll
    for (int off = 32; off >= 1; off >>= 1) v += __shfl_xor(v, off);
    return v;
}

__device__ __forceinline__ int wave_incl_scan(int v, int lane) {
#pragma unroll
    for (int off = 1; off < 64; off <<= 1) {
        int t = __shfl_up(v, off);
        if (lane >= off) v += t;
    }
    return v;
}

// ---------------------------------------------------------------- CSR build
__global__ void k_hist(const int* __restrict__ dst, int* __restrict__ cnt) {
    int e = blockIdx.x * 256 + threadIdx.x;
    if (e < N_EDGES) atomicAdd(&cnt[dst[e]], 1);
}

// scan of PADDED counts (each row rounded up to multiple of 4)
__global__ void k_scan1(const int* __restrict__ cnt, int* __restrict__ rowptr,
                        int* __restrict__ blocksum) {
    __shared__ int wsum[16];
    int tid = threadIdx.x;
    int gid = blockIdx.x * 1024 + tid;
    int lane = tid & 63, wid = tid >> 6;
    int v = (gid < N_NODES) ? ((cnt[gid] + 3) & ~3) : 0;
    int incl = wave_incl_scan(v, lane);
    if (lane == 63) wsum[wid] = incl;
    __syncthreads();
    if (wid == 0) {
        int wv = (lane < 16) ? wsum[lane] : 0;
        int wincl = wave_incl_scan(wv, lane);
        if (lane < 16) wsum[lane] = wincl - wv;
    }
    __syncthreads();
    int excl = incl - v + wsum[wid];
    if (gid < N_NODES) rowptr[gid] = excl;
    if (tid == 1023) blocksum[blockIdx.x] = excl + v;
}

__global__ void k_scan2(int* __restrict__ blocksum, int* __restrict__ rowptr) {
    int lane = threadIdx.x;
    int v = (lane < SCAN_NB) ? blocksum[lane] : 0;
    int incl = wave_incl_scan(v, lane);
    if (lane < SCAN_NB) blocksum[lane] = incl - v;
    if (lane == SCAN_NB - 1) rowptr[N_NODES] = incl;  // padded total
}

__global__ void k_scan3(int* __restrict__ rowptr, const int* __restrict__ blocksum,
                        int* __restrict__ cursor) {
    int tid = threadIdx.x;
    int gid = blockIdx.x * 1024 + tid;
    if (gid < N_NODES) {
        int r = rowptr[gid] + blocksum[blockIdx.x];
        rowptr[gid] = r;
        cursor[gid] = r;
    }
}

// csr_sd pre-memset to 0xFF (-1): pad slots stay sentinel
__global__ void k_scatter(const int* __restrict__ src, const int* __restrict__ dst,
                          int* __restrict__ cursor, int2* __restrict__ csr_sd) {
    int e = blockIdx.x * 256 + threadIdx.x;
    if (e < N_EDGES) {
        int d = dst[e];
        int pos = atomicAdd(&cursor[d], 1);
        csr_sd[pos] = make_int2(src[e], d);
    }
}

// ---------------------------------------------------------------- weight f32 -> hi/lo bf16
struct WSrc {
    const float* s[7];
    int off[8];
};
__global__ void k_cvt_w(WSrc ws, ushort_t* __restrict__ hi, ushort_t* __restrict__ lo) {
    int gid = blockIdx.x * 256 + threadIdx.x;
    int stride = gridDim.x * 256;
#pragma unroll
    for (int mi = 0; mi < 7; mi++) {
        int n = ws.off[mi + 1] - ws.off[mi];
        const float* s = ws.s[mi];
        ushort_t* h = hi + ws.off[mi];
        ushort_t* l = lo + ws.off[mi];
        for (int i = gid; i < n; i += stride) {
            float f = s[i];
            ushort_t hb = f2bf(f);
            h[i] = hb;
            l[i] = f2bf(f - bf2f(hb));
        }
    }
}

// ---------------------------------------------------------------- dual projection via MFMA
template <int K, bool A_FP32>
__global__ void k_gemm_dual_mfma(const void* __restrict__ xa,
                                 const ushort_t* __restrict__ wlh, const ushort_t* __restrict__ wll,
                                 const ushort_t* __restrict__ wrh, const ushort_t* __restrict__ wrl,
                                 const float* __restrict__ bl, const float* __restrict__ br,
                                 ushort_t* __restrict__ xl, ushort_t* __restrict__ xr) {
    int tid = threadIdx.x;
    int wv = tid >> 6, lane = tid & 63;
    int m0 = blockIdx.x * 64 + wv * 16;
    if (m0 >= N_NODES) return;
    int arow = min(m0 + (lane & 15), N_NODES - 1);
    int koff = (lane >> 4) * 8;
    int wrow = lane & 15;

    float4v acc[8];
#pragma unroll
    for (int f = 0; f < 8; f++) acc[f] = (float4v)(0.f);

#pragma unroll
    for (int k0 = 0; k0 < K; k0 += 32) {
        short8v afrag;
        if (A_FP32) {
            const float* ap = (const float*)xa + (size_t)arow * K + k0 + koff;
            float4 a0 = *reinterpret_cast<const float4*>(ap);
            float4 a1 = *reinterpret_cast<const float4*>(ap + 4);
            afrag[0] = (short)f2bf(a0.x); afrag[1] = (short)f2bf(a0.y);
            afrag[2] = (short)f2bf(a0.z); afrag[3] = (short)f2bf(a0.w);
            afrag[4] = (short)f2bf(a1.x); afrag[5] = (short)f2bf(a1.y);
            afrag[6] = (short)f2bf(a1.z); afrag[7] = (short)f2bf(a1.w);
        } else {
            afrag = *reinterpret_cast<const short8v*>((const ushort_t*)xa + (size_t)arow * K + k0 + koff);
        }
#pragma unroll
        for (int f = 0; f < 8; f++) {
            const ushort_t* bh = (f < 4) ? wlh : wrh;
            const ushort_t* blo = (f < 4) ? wll : wrl;
            int row = ((f * 16 + wrow) & 63);
            size_t boff = (size_t)row * K + k0 + koff;
            short8v bfh = *reinterpret_cast<const short8v*>(bh + boff);
            short8v bfl = *reinterpret_cast<const short8v*>(blo + boff);
            acc[f] = __builtin_amdgcn_mfma_f32_16x16x32_bf16(afrag, bfh, acc[f], 0, 0, 0);
            acc[f] = __builtin_amdgcn_mfma_f32_16x16x32_bf16(afrag, bfl, acc[f], 0, 0, 0);
        }
    }

    int r0 = m0 + (lane >> 4) * 4;
#pragma unroll
    for (int f = 0; f < 8; f++) {
        int col = f * 16 + (lane & 15);
        float bias = (col < 64) ? bl[col] : br[col - 64];
        ushort_t* dstp = (col < 64) ? xl : xr;
        int c = col & 63;
#pragma unroll
        for (int j = 0; j < 4; j++) {
            int row = r0 + j;
            if (row < N_NODES) dstp[(size_t)row * 64 + c] = f2bf(acc[f][j] + bias);
        }
    }
}

// ---------------------------------------------------------------- h = relu(concat @ lin1_w.T + b)
__global__ void k_gemm_h_mfma(const ushort_t* __restrict__ x1, const ushort_t* __restrict__ x2,
                              const ushort_t* __restrict__ x3,
                              const ushort_t* __restrict__ whi, const ushort_t* __restrict__ wlo,
                              const float* __restrict__ b, float* __restrict__ h) {
    int tid = threadIdx.x;
    int wv = tid >> 6, lane = tid & 63;
    int m0 = blockIdx.x * 64 + wv * 16;
    if (m0 >= N_NODES) return;
    int arow = min(m0 + (lane & 15), N_NODES - 1);
    int koff = (lane >> 4) * 8;
    int wrow = lane & 15;

    float4v acc[4];
#pragma unroll
    for (int f = 0; f < 4; f++) acc[f] = (float4v)(0.f);

#pragma unroll
    for (int ks = 0; ks < 6; ks++) {
        int k0 = ks * 32;
        const ushort_t* srcp = (ks < 2) ? x1 : (ks < 4 ? x2 : x3);
        int kc = k0 & 63;
        short8v afrag = *reinterpret_cast<const short8v*>(srcp + (size_t)arow * 64 + kc + koff);
#pragma unroll
        for (int f = 0; f < 4; f++) {
            size_t boff = (size_t)(f * 16 + wrow) * 192 + k0 + koff;
            short8v bfh = *reinterpret_cast<const short8v*>(whi + boff);
            short8v bfl = *reinterpret_cast<const short8v*>(wlo + boff);
            acc[f] = __builtin_amdgcn_mfma_f32_16x16x32_bf16(afrag, bfh, acc[f], 0, 0, 0);
            acc[f] = __builtin_amdgcn_mfma_f32_16x16x32_bf16(afrag, bfl, acc[f], 0, 0, 0);
        }
    }

    int r0 = m0 + (lane >> 4) * 4;
#pragma unroll
    for (int f = 0; f < 4; f++) {
        int col = f * 16 + (lane & 15);
        float bias = b[col];
#pragma unroll
        for (int j = 0; j < 4; j++) {
            int row = r0 + j;
            if (row < N_NODES) {
                float o = acc[f][j] + bias;
                h[(size_t)row * 64 + col] = o > 0.f ? o : 0.f;
            }
        }
    }
}

// ---------------------------------------------------------------- edge scores (edge-parallel)
// 8 lanes per edge, 8 edges per wave; lane owns 8 channels (16B bf16 loads)
__global__ void k_escore(const ushort_t* __restrict__ xl, const ushort_t* __restrict__ xr,
                         const int2* __restrict__ csr_sd, const float* __restrict__ att,
                         float* __restrict__ e_scr) {
    int tid = threadIdx.x;
    int wv = tid >> 6, lane = tid & 63;
    int ebase = blockIdx.x * 32 + wv * 8;
    int g = lane >> 3;
    int sub = lane & 7;
    int c0 = sub * 8;

    int2 sd = csr_sd[ebase + g];
    bool valid = sd.x >= 0;
    int sj = valid ? sd.x : 0;
    int dj = valid ? sd.y : 0;

    short8v a = *reinterpret_cast<const short8v*>(xl + (size_t)sj * 64 + c0);
    short8v b = *reinterpret_cast<const short8v*>(xr + (size_t)dj * 64 + c0);
    float4 at0 = *reinterpret_cast<const float4*>(att + c0);
    float4 at1 = *reinterpret_cast<const float4*>(att + c0 + 4);
    float atv[8] = {at0.x, at0.y, at0.z, at0.w, at1.x, at1.y, at1.z, at1.w};

    float p = 0.f;
#pragma unroll
    for (int k = 0; k < 8; k++) {
        float s = bf2f((ushort_t)a[k]) + bf2f((ushort_t)b[k]);
        float t = (s > 0.f ? s : LRELU_SLOPE * s);
        p += t * atv[k];
    }
    p += __shfl_xor(p, 1);
    p += __shfl_xor(p, 2);
    p += __shfl_xor(p, 4);
    if (sub == 0) e_scr[ebase + g] = valid ? p : NEG_INF_SCORE;
}

// ---------------------------------------------------------------- GAT aggregate (wave per node, 2-pass)
__global__ void k_gat_agg(const ushort_t* __restrict__ xl, const ushort_t* __restrict__ xr,
                          const int* __restrict__ rowptr, const int2* __restrict__ csr_sd,
                          const float* __restrict__ e_scr, const float* __restrict__ att,
                          const float* __restrict__ bo, ushort_t* __restrict__ xout) {
    int wid = blockIdx.x * 4 + (threadIdx.x >> 6);
    int lane = threadIdx.x & 63;
    if (wid >= N_NODES) return;
    float attv = att[lane];
    float xrv = bf2f(xr[(size_t)wid * 64 + lane]);
    float xls = bf2f(xl[(size_t)wid * 64 + lane]);
    int beg = rowptr[wid], end = rowptr[wid + 1];   // multiples of 4

    float s = xls + xrv;
    float t = (s > 0.f ? s : LRELU_SLOPE * s) * attv;
    float e_self = wave_sum(t);

    // pass 1: true max
    float m = e_self;
    for (int j = beg; j < end; j += 4) {
        float4 e4 = *reinterpret_cast<const float4*>(e_scr + j);
        m = fmaxf(m, fmaxf(fmaxf(e4.x, e4.y), fmaxf(e4.z, e4.w)));
    }

    // pass 2: weighted gather-sum
    float ssum = __expf(e_self - m);
    float acc = ssum * xls;
    for (int j = beg; j < end; j += 4) {
        float4 e4 = *reinterpret_cast<const float4*>(e_scr + j);
        int s0 = csr_sd[j + 0].x, s1 = csr_sd[j + 1].x;
        int s2 = csr_sd[j + 2].x, s3 = csr_sd[j + 3].x;
        s0 = s0 < 0 ? 0 : s0; s1 = s1 < 0 ? 0 : s1;
        s2 = s2 < 0 ? 0 : s2; s3 = s3 < 0 ? 0 : s3;
        float w0 = __expf(e4.x - m), w1 = __expf(e4.y - m);
        float w2 = __expf(e4.z - m), w3 = __expf(e4.w - m);
        float v0 = bf2f(xl[(size_t)s0 * 64 + lane]);
        float v1 = bf2f(xl[(size_t)s1 * 64 + lane]);
        float v2 = bf2f(xl[(size_t)s2 * 64 + lane]);
        float v3 = bf2f(xl[(size_t)s3 * 64 + lane]);
        ssum += (w0 + w1) + (w2 + w3);
        acc += (w0 * v0 + w1 * v1) + (w2 * v2 + w3 * v3);
    }

    float o = acc / (ssum + 1e-16f) + bo[lane];
    xout[(size_t)wid * 64 + lane] = f2bf(o > 0.f ? o : 0.f);
}

// ---------------------------------------------------------------- global_add_pool (batch_idx sorted)
__global__ void k_pool(const float* __restrict__ h, const int* __restrict__ batch,
                       float* __restrict__ g) {
    __shared__ float red[4][64];
    int base = blockIdx.x * 32;
    if (base >= N_NODES) return;
    int tid = threadIdx.x;
    int c = tid & 63;
    int rr = tid >> 6;
    int lastIdx = min(base + 31, N_NODES - 1);
    int b0 = batch[base];
    bool uniform = (batch[lastIdx] == b0);
    if (uniform) {
        float acc = 0.f;
        for (int r = rr; r < 32; r += 4) {
            int i = base + r;
            if (i < N_NODES) acc += h[(size_t)i * 64 + c];
        }
        red[rr][c] = acc;
        __syncthreads();
        if (rr == 0) {
            float sum = red[0][c] + red[1][c] + red[2][c] + red[3][c];
            atomicAdd(&g[b0 * 64 + c], sum);
        }
    } else {
        for (int r = rr; r < 32; r += 4) {
            int i = base + r;
            if (i < N_NODES) atomicAdd(&g[batch[i] * 64 + c], h[(size_t)i * 64 + c]);
        }
    }
}

// ---------------------------------------------------------------- head
__global__ void k_head(const float* __restrict__ g, const float* __restrict__ pw,
                       const float* __restrict__ pb, const float* __restrict__ cw,
                       const float* __restrict__ cb, float* __restrict__ out) {
    int gb = blockIdx.x;
    int c = threadIdx.x;
    const float* gr = g + gb * 64;
    float a = pb[c];
    const float* pwr = pw + c * 64;
#pragma unroll
    for (int k = 0; k < 64; k++) a += gr[k] * pwr[k];
    a = a > 0.f ? a : 0.f;
    float o0 = wave_sum(a * cw[c]);
    float o1 = wave_sum(a * cw[64 + c]);
    if (c == 0) {
        out[gb * 2 + 0] = o0 + cb[0];
        out[gb * 2 + 1] = o1 + cb[1];
    }
}

// ---------------------------------------------------------------- launcher
extern "C" void kernel_launch(void* const* d_in, const int* in_sizes, int n_in,
                              void* d_out, int out_size, void* d_ws, size_t ws_size,
                              hipStream_t stream) {
    const float* x    = (const float*)d_in[0];
    const int*   ei   = (const int*)d_in[1];
    const int*   bidx = (const int*)d_in[2];
    const float* wl1 = (const float*)d_in[3],  *bl1 = (const float*)d_in[4];
    const float* wr1 = (const float*)d_in[5],  *br1 = (const float*)d_in[6];
    const float* att1 = (const float*)d_in[7], *bo1 = (const float*)d_in[8];
    const float* wl2 = (const float*)d_in[9],  *bl2 = (const float*)d_in[10];
    const float* wr2 = (const float*)d_in[11], *br2 = (const float*)d_in[12];
    const float* att2 = (const float*)d_in[13], *bo2 = (const float*)d_in[14];
    const float* wl3 = (const float*)d_in[15], *bl3 = (const float*)d_in[16];
    const float* wr3 = (const float*)d_in[17], *br3 = (const float*)d_in[18];
    const float* att3 = (const float*)d_in[19], *bo3 = (const float*)d_in[20];
    const float* lw = (const float*)d_in[21], *lb = (const float*)d_in[22];
    const float* pw = (const float*)d_in[23], *pb = (const float*)d_in[24];
    const float* cw = (const float*)d_in[25], *cb = (const float*)d_in[26];
    float* out = (float*)d_out;

    char* wsb = (char*)d_ws;
    size_t off = 0;
    auto alloc = [&](size_t bytes) {
        void* p = wsb + off;
        off = (off + bytes + 255) & ~(size_t)255;
        return p;
    };
    int* cnt      = (int*)alloc((size_t)N_NODES * 4);
    int* rowptr   = (int*)alloc((size_t)(N_NODES + 1) * 4);
    int* cursor   = (int*)alloc((size_t)N_NODES * 4);
    int* blocksum = (int*)alloc((size_t)SCAN_NB * 4);
    int2* csr_sd  = (int2*)alloc((size_t)NE_PAD_MAX * 8);
    float* e_scr  = (float*)alloc((size_t)NE_PAD_MAX * 4);
    const int woff[8] = {0, 8192, 16384, 20480, 24576, 28672, 32768, 45056};
    ushort_t* whi = (ushort_t*)alloc((size_t)45056 * 2);
    ushort_t* wlo = (ushort_t*)alloc((size_t)45056 * 2);
    ushort_t* xl   = (ushort_t*)alloc((size_t)N_NODES * 64 * 2);
    ushort_t* xrr  = (ushort_t*)alloc((size_t)N_NODES * 64 * 2);
    ushort_t* x1b  = (ushort_t*)alloc((size_t)N_NODES * 64 * 2);
    ushort_t* x2b  = (ushort_t*)alloc((size_t)N_NODES * 64 * 2);
    ushort_t* x3b  = (ushort_t*)alloc((size_t)N_NODES * 64 * 2);
    float* hb     = (float*)alloc((size_t)N_NODES * 64 * 4);
    float* g      = (float*)alloc((size_t)NGRAPH * 64 * 4);
    (void)ws_size; (void)in_sizes; (void)n_in; (void)out_size;

    const int* srcp = ei;
    const int* dstp = ei + N_EDGES;

    hipMemsetAsync(cnt, 0, (size_t)N_NODES * 4, stream);
    hipMemsetAsync(g, 0, (size_t)NGRAPH * 64 * 4, stream);
    hipMemsetAsync(csr_sd, 0xFF, (size_t)NE_PAD_MAX * 8, stream);  // all-sentinel (-1)

    k_hist<<<N_EDGES / 256, 256, 0, stream>>>(dstp, cnt);
    k_scan1<<<SCAN_NB, 1024, 0, stream>>>(cnt, rowptr, blocksum);
    k_scan2<<<1, 64, 0, stream>>>(blocksum, rowptr);
    k_scan3<<<SCAN_NB, 1024, 0, stream>>>(rowptr, blocksum, cursor);
    k_scatter<<<N_EDGES / 256, 256, 0, stream>>>(srcp, dstp, cursor, csr_sd);

    WSrc ws;
    ws.s[0] = wl1; ws.s[1] = wr1; ws.s[2] = wl2; ws.s[3] = wr2;
    ws.s[4] = wl3; ws.s[5] = wr3; ws.s[6] = lw;
    for (int i = 0; i < 8; i++) ws.off[i] = woff[i];
    k_cvt_w<<<64, 256, 0, stream>>>(ws, whi, wlo);

    int gemmBlocks = (N_NODES + 63) / 64;
    int gatBlocks = (N_NODES + 3) / 4;
    int escBlocks = NE_PAD_MAX / 32;   // 8 edges/wave * 4 waves

    // layer 1
    k_gemm_dual_mfma<128, true><<<gemmBlocks, 256, 0, stream>>>(
        x, whi + woff[0], wlo + woff[0], whi + woff[1], wlo + woff[1], bl1, br1, xl, xrr);
    k_escore<<<escBlocks, 256, 0, stream>>>(xl, xrr, csr_sd, att1, e_scr);
    k_gat_agg<<<gatBlocks, 256, 0, stream>>>(xl, xrr, rowptr, csr_sd, e_scr, att1, bo1, x1b);
    // layer 2
    k_gemm_dual_mfma<64, false><<<gemmBlocks, 256, 0, stream>>>(
        x1b, whi + woff[2], wlo + woff[2], whi + woff[3], wlo + woff[3], bl2, br2, xl, xrr);
    k_escore<<<escBlocks, 256, 0, stream>>>(xl, xrr, csr_sd, att2, e_scr);
    k_gat_agg<<<gatBlocks, 256, 0, stream>>>(xl, xrr, rowptr, csr_sd, e_scr, att2, bo2, x2b);
    // layer 3
    k_gemm_dual_mfma<64, false><<<gemmBlocks, 256, 0, stream>>>(
        x2b, whi + woff[4], wlo + woff[4], whi + woff[5], wlo + woff[5], bl3, br3, xl, xrr);
    k_escore<<<escBlocks, 256, 0, stream>>>(xl, xrr, csr_sd, att3, e_scr);
    k_gat_agg<<<gatBlocks, 256, 0, stream>>>(xl, xrr, rowptr, csr_sd, e_scr, att3, bo3, x3b);

    // head
    k_gemm_h_mfma<<<gemmBlocks, 256, 0, stream>>>(x1b, x2b, x3b, whi + woff[6], wlo + woff[6], lb, hb);
    k_pool<<<(N_NODES + 31) / 32, 256, 0, stream>>>(hb, bidx, g);
    k_head<<<NGRAPH, 64, 0, stream>>>(g, pw, pb, cw, cb, out);
}

// Round 6
// 337.657 us; speedup vs baseline: 1.3382x; 1.3382x over previous
//
#include <hip/hip_runtime.h>
#include <hip/hip_bf16.h>

#define N_NODES 50000
#define N_EDGES 800000
#define FDIM 128
#define CDIM 64
#define NGRAPH 256
#define LRELU_SLOPE 0.2f
#define SCAN_NB ((N_NODES + 1023) / 1024)   // 49
#define NBUCK ((N_NODES + 255) / 256)       // 196 buckets of 256 nodes
#define BCAP 5120                            // stage capacity/bucket (mean 4082, 16 sigma)
#define ABLK 200                             // pass-A blocks
#define EPB ((N_EDGES + ABLK - 1) / ABLK)    // 4000 edges per pass-A block

typedef unsigned short ushort_t;
typedef unsigned int uint_t;
typedef __attribute__((ext_vector_type(8))) short short8v;
typedef __attribute__((ext_vector_type(4))) float float4v;

// ---------------------------------------------------------------- bf16 helpers (RNE)
__device__ __forceinline__ ushort_t f2bf(float f) {
    uint_t u = __float_as_uint(f);
    u += 0x7FFFu + ((u >> 16) & 1u);
    return (ushort_t)(u >> 16);
}
__device__ __forceinline__ float bf2f(ushort_t u) {
    return __uint_as_float(((uint_t)u) << 16);
}

__device__ __forceinline__ float wave_sum(float v) {
#pragma unroll
    for (int off = 32; off >= 1; off >>= 1) v += __shfl_xor(v, off);
    return v;
}

__device__ __forceinline__ void wave_sum4(float& a, float& b, float& c, float& d) {
#pragma unroll
    for (int off = 32; off >= 1; off >>= 1) {
        a += __shfl_xor(a, off);
        b += __shfl_xor(b, off);
        c += __shfl_xor(c, off);
        d += __shfl_xor(d, off);
    }
}

__device__ __forceinline__ int wave_incl_scan(int v, int lane) {
#pragma unroll
    for (int off = 1; off < 64; off <<= 1) {
        int t = __shfl_up(v, off);
        if (lane >= off) v += t;
    }
    return v;
}

// ---------------------------------------------------------------- CSR build, locality 2-pass
// pass A: bucket edges by dst>>8 into stage (block-local LDS hist + one global reserve per block*bucket)
__global__ void k_bucket(const int* __restrict__ src, const int* __restrict__ dst,
                         int* __restrict__ bcnt, int2* __restrict__ stage) {
    __shared__ int lhist[NBUCK];
    __shared__ int lbase[NBUCK];
    __shared__ int lcur[NBUCK];
    int tid = threadIdx.x;
    int e0 = blockIdx.x * EPB;
    int e1 = min(e0 + EPB, N_EDGES);
    for (int t = tid; t < NBUCK; t += 256) { lhist[t] = 0; lcur[t] = 0; }
    __syncthreads();
    for (int e = e0 + tid; e < e1; e += 256)
        atomicAdd(&lhist[dst[e] >> 8], 1);
    __syncthreads();
    for (int t = tid; t < NBUCK; t += 256)
        lbase[t] = atomicAdd(&bcnt[t], lhist[t]);
    __syncthreads();
    for (int e = e0 + tid; e < e1; e += 256) {
        int s = src[e], d = dst[e];
        int b = d >> 8;
        int loff = atomicAdd(&lcur[b], 1);
        int pos = lbase[b] + loff;
        if (pos < BCAP) stage[(size_t)b * BCAP + pos] = make_int2(s, d);
    }
}

// per-bucket node histogram from staged edges (LDS counters, contiguous stores)
__global__ void k_hist2(const int* __restrict__ bcnt, const int2* __restrict__ stage,
                        int* __restrict__ cnt) {
    __shared__ int lcnt[256];
    int b = blockIdx.x;
    int tid = threadIdx.x;
    lcnt[tid] = 0;
    __syncthreads();
    int n = min(bcnt[b], BCAP);
    const int2* sp = stage + (size_t)b * BCAP;
    for (int i = tid; i < n; i += 256)
        atomicAdd(&lcnt[sp[i].y & 255], 1);
    __syncthreads();
    int node = (b << 8) + tid;
    if (node < N_NODES) cnt[node] = lcnt[tid];
}

__global__ void k_scan1(const int* __restrict__ cnt, int* __restrict__ rowptr,
                        int* __restrict__ blocksum) {
    __shared__ int wsum[16];
    int tid = threadIdx.x;
    int gid = blockIdx.x * 1024 + tid;
    int lane = tid & 63, wid = tid >> 6;
    int v = (gid < N_NODES) ? cnt[gid] : 0;
    int incl = wave_incl_scan(v, lane);
    if (lane == 63) wsum[wid] = incl;
    __syncthreads();
    if (wid == 0) {
        int wv = (lane < 16) ? wsum[lane] : 0;
        int wincl = wave_incl_scan(wv, lane);
        if (lane < 16) wsum[lane] = wincl - wv;
    }
    __syncthreads();
    int excl = incl - v + wsum[wid];
    if (gid < N_NODES) rowptr[gid] = excl;
    if (tid == 1023) blocksum[blockIdx.x] = excl + v;
}

__global__ void k_scan2(int* __restrict__ blocksum) {
    int lane = threadIdx.x;
    int v = (lane < SCAN_NB) ? blocksum[lane] : 0;
    int incl = wave_incl_scan(v, lane);
    if (lane < SCAN_NB) blocksum[lane] = incl - v;
}

__global__ void k_scan3(int* __restrict__ rowptr, const int* __restrict__ blocksum,
                        int* __restrict__ cursor) {
    int tid = threadIdx.x;
    int gid = blockIdx.x * 1024 + tid;
    if (gid < N_NODES) {
        int r = rowptr[gid] + blocksum[blockIdx.x];
        rowptr[gid] = r;
        cursor[gid] = r;
    }
    if (blockIdx.x == 0 && tid == 0) rowptr[N_NODES] = N_EDGES;
}

// pass B: per-bucket scatter into CSR rows (16KB contiguous window -> L2-local writes)
__global__ void k_scatter2(const int* __restrict__ bcnt, const int2* __restrict__ stage,
                           int* __restrict__ cursor, int* __restrict__ csr_src) {
    int b = blockIdx.x;
    int tid = threadIdx.x;
    int n = min(bcnt[b], BCAP);
    const int2* sp = stage + (size_t)b * BCAP;
    for (int i = tid; i < n; i += 256) {
        int2 sd = sp[i];
        int pos = atomicAdd(&cursor[sd.y], 1);
        csr_src[pos] = sd.x;
    }
}

// ---------------------------------------------------------------- weight f32 -> hi/lo bf16
struct WSrc {
    const float* s[7];
    int off[8];
};
__global__ void k_cvt_w(WSrc ws, ushort_t* __restrict__ hi, ushort_t* __restrict__ lo) {
    int gid = blockIdx.x * 256 + threadIdx.x;
    int stride = gridDim.x * 256;
#pragma unroll
    for (int mi = 0; mi < 7; mi++) {
        int n = ws.off[mi + 1] - ws.off[mi];
        const float* s = ws.s[mi];
        ushort_t* h = hi + ws.off[mi];
        ushort_t* l = lo + ws.off[mi];
        for (int i = gid; i < n; i += stride) {
            float f = s[i];
            ushort_t hb = f2bf(f);
            h[i] = hb;
            l[i] = f2bf(f - bf2f(hb));
        }
    }
}

// ---------------------------------------------------------------- dual projection via MFMA
template <int K, bool A_FP32>
__global__ void k_gemm_dual_mfma(const void* __restrict__ xa,
                                 const ushort_t* __restrict__ wlh, const ushort_t* __restrict__ wll,
                                 const ushort_t* __restrict__ wrh, const ushort_t* __restrict__ wrl,
                                 const float* __restrict__ bl, const float* __restrict__ br,
                                 ushort_t* __restrict__ xl, ushort_t* __restrict__ xr) {
    int tid = threadIdx.x;
    int wv = tid >> 6, lane = tid & 63;
    int m0 = blockIdx.x * 64 + wv * 16;
    if (m0 >= N_NODES) return;
    int arow = min(m0 + (lane & 15), N_NODES - 1);
    int koff = (lane >> 4) * 8;
    int wrow = lane & 15;

    float4v acc[8];
#pragma unroll
    for (int f = 0; f < 8; f++) acc[f] = (float4v)(0.f);

#pragma unroll
    for (int k0 = 0; k0 < K; k0 += 32) {
        short8v afrag;
        if (A_FP32) {
            const float* ap = (const float*)xa + (size_t)arow * K + k0 + koff;
            float4 a0 = *reinterpret_cast<const float4*>(ap);
            float4 a1 = *reinterpret_cast<const float4*>(ap + 4);
            afrag[0] = (short)f2bf(a0.x); afrag[1] = (short)f2bf(a0.y);
            afrag[2] = (short)f2bf(a0.z); afrag[3] = (short)f2bf(a0.w);
            afrag[4] = (short)f2bf(a1.x); afrag[5] = (short)f2bf(a1.y);
            afrag[6] = (short)f2bf(a1.z); afrag[7] = (short)f2bf(a1.w);
        } else {
            afrag = *reinterpret_cast<const short8v*>((const ushort_t*)xa + (size_t)arow * K + k0 + koff);
        }
#pragma unroll
        for (int f = 0; f < 8; f++) {
            const ushort_t* bh = (f < 4) ? wlh : wrh;
            const ushort_t* blo = (f < 4) ? wll : wrl;
            int row = ((f * 16 + wrow) & 63);
            size_t boff = (size_t)row * K + k0 + koff;
            short8v bfh = *reinterpret_cast<const short8v*>(bh + boff);
            short8v bfl = *reinterpret_cast<const short8v*>(blo + boff);
            acc[f] = __builtin_amdgcn_mfma_f32_16x16x32_bf16(afrag, bfh, acc[f], 0, 0, 0);
            acc[f] = __builtin_amdgcn_mfma_f32_16x16x32_bf16(afrag, bfl, acc[f], 0, 0, 0);
        }
    }

    int r0 = m0 + (lane >> 4) * 4;
#pragma unroll
    for (int f = 0; f < 8; f++) {
        int col = f * 16 + (lane & 15);
        float bias = (col < 64) ? bl[col] : br[col - 64];
        ushort_t* dstp = (col < 64) ? xl : xr;
        int c = col & 63;
#pragma unroll
        for (int j = 0; j < 4; j++) {
            int row = r0 + j;
            if (row < N_NODES) dstp[(size_t)row * 64 + c] = f2bf(acc[f][j] + bias);
        }
    }
}

// ---------------------------------------------------------------- h = relu(concat @ lin1_w.T + b)
__global__ void k_gemm_h_mfma(const ushort_t* __restrict__ x1, const ushort_t* __restrict__ x2,
                              const ushort_t* __restrict__ x3,
                              const ushort_t* __restrict__ whi, const ushort_t* __restrict__ wlo,
                              const float* __restrict__ b, float* __restrict__ h) {
    int tid = threadIdx.x;
    int wv = tid >> 6, lane = tid & 63;
    int m0 = blockIdx.x * 64 + wv * 16;
    if (m0 >= N_NODES) return;
    int arow = min(m0 + (lane & 15), N_NODES - 1);
    int koff = (lane >> 4) * 8;
    int wrow = lane & 15;

    float4v acc[4];
#pragma unroll
    for (int f = 0; f < 4; f++) acc[f] = (float4v)(0.f);

#pragma unroll
    for (int ks = 0; ks < 6; ks++) {
        int k0 = ks * 32;
        const ushort_t* srcp = (ks < 2) ? x1 : (ks < 4 ? x2 : x3);
        int kc = k0 & 63;
        short8v afrag = *reinterpret_cast<const short8v*>(srcp + (size_t)arow * 64 + kc + koff);
#pragma unroll
        for (int f = 0; f < 4; f++) {
            size_t boff = (size_t)(f * 16 + wrow) * 192 + k0 + koff;
            short8v bfh = *reinterpret_cast<const short8v*>(whi + boff);
            short8v bfl = *reinterpret_cast<const short8v*>(wlo + boff);
            acc[f] = __builtin_amdgcn_mfma_f32_16x16x32_bf16(afrag, bfh, acc[f], 0, 0, 0);
            acc[f] = __builtin_amdgcn_mfma_f32_16x16x32_bf16(afrag, bfl, acc[f], 0, 0, 0);
        }
    }

    int r0 = m0 + (lane >> 4) * 4;
#pragma unroll
    for (int f = 0; f < 4; f++) {
        int col = f * 16 + (lane & 15);
        float bias = b[col];
#pragma unroll
        for (int j = 0; j < 4; j++) {
            int row = r0 + j;
            if (row < N_NODES) {
                float o = acc[f][j] + bias;
                h[(size_t)row * 64 + col] = o > 0.f ? o : 0.f;
            }
        }
    }
}

// ---------------------------------------------------------------- GATv2 aggregate: one wave per dst node
// fused single-pass online softmax (round-4 version: 52.7us/layer measured)
__global__ void k_gat(const ushort_t* __restrict__ xl, const ushort_t* __restrict__ xr,
                      const int* __restrict__ rowptr, const int* __restrict__ csr_src,
                      const float* __restrict__ att, const float* __restrict__ bo,
                      ushort_t* __restrict__ xout) {
    int wid = blockIdx.x * 4 + (threadIdx.x >> 6);
    int lane = threadIdx.x & 63;
    if (wid >= N_NODES) return;
    float attv = att[lane];
    float xrv = bf2f(xr[(size_t)wid * 64 + lane]);
    float xls = bf2f(xl[(size_t)wid * 64 + lane]);
    int beg = rowptr[wid], end = rowptr[wid + 1];

    float s = xls + xrv;
    float t = (s > 0.f ? s : LRELU_SLOPE * s) * attv;
    float m = wave_sum(t);
    float ssum = 1.0f;
    float acc = xls;

    bool b0 = (lane & 1) != 0;
    bool b1 = (lane & 2) != 0;

    int j = beg;
    for (; j + 4 <= end; j += 4) {
        int s0 = csr_src[j + 0], s1 = csr_src[j + 1];
        int s2 = csr_src[j + 2], s3 = csr_src[j + 3];
        float v0 = bf2f(xl[(size_t)s0 * 64 + lane]);
        float v1 = bf2f(xl[(size_t)s1 * 64 + lane]);
        float v2 = bf2f(xl[(size_t)s2 * 64 + lane]);
        float v3 = bf2f(xl[(size_t)s3 * 64 + lane]);
        float a0 = v0 + xrv, a1 = v1 + xrv, a2 = v2 + xrv, a3 = v3 + xrv;
        float t0 = (a0 > 0.f ? a0 : LRELU_SLOPE * a0) * attv;
        float t1 = (a1 > 0.f ? a1 : LRELU_SLOPE * a1) * attv;
        float t2 = (a2 > 0.f ? a2 : LRELU_SLOPE * a2) * attv;
        float t3 = (a3 > 0.f ? a3 : LRELU_SLOPE * a3) * attv;

        float c = (b0 ? t1 : t0) + __shfl_xor(b0 ? t0 : t1, 1);
        float d = (b0 ? t3 : t2) + __shfl_xor(b0 ? t2 : t3, 1);
        float e = (b1 ? d : c) + __shfl_xor(b1 ? c : d, 2);
        e += __shfl_xor(e, 4);
        e += __shfl_xor(e, 8);
        e += __shfl_xor(e, 16);
        e += __shfl_xor(e, 32);
        float f0 = e;
        float f1 = __shfl_xor(e, 1);
        float f2 = __shfl_xor(e, 2);
        float f3 = __shfl_xor(f2, 1);

        float mn = fmaxf(fmaxf(fmaxf(f0, f1), fmaxf(f2, f3)), m);
        float sc = __expf(m - mn);
        float w0 = __expf(f0 - mn), w1 = __expf(f1 - mn);
        float w2 = __expf(f2 - mn), w3 = __expf(f3 - mn);
        ssum = ssum * sc + ((w0 + w1) + (w2 + w3));

        float x01 = b0 ? v1 : v0, x01b = b0 ? v0 : v1;
        float x23 = b0 ? v3 : v2, x23b = b0 ? v2 : v3;
        float vp0 = b1 ? x23 : x01, vp2 = b1 ? x01 : x23;
        float vp1 = b1 ? x23b : x01b, vp3 = b1 ? x01b : x23b;
        acc = acc * sc + ((w0 * vp0 + w1 * vp1) + (w2 * vp2 + w3 * vp3));
        m = mn;
    }
    for (; j < end; j++) {
        int sj = csr_src[j];
        float v = bf2f(xl[(size_t)sj * 64 + lane]);
        float a = v + xrv;
        float tt = (a > 0.f ? a : LRELU_SLOPE * a) * attv;
        float e = wave_sum(tt);
        float mn = fmaxf(m, e);
        float sc = __expf(m - mn);
        float w = __expf(e - mn);
        ssum = ssum * sc + w;
        acc = acc * sc + w * v;
        m = mn;
    }

    float o = acc / (ssum + 1e-16f) + bo[lane];
    xout[(size_t)wid * 64 + lane] = f2bf(o > 0.f ? o : 0.f);
}

// ---------------------------------------------------------------- global_add_pool (batch_idx sorted)
__global__ void k_pool(const float* __restrict__ h, const int* __restrict__ batch,
                       float* __restrict__ g) {
    __shared__ float red[4][64];
    int base = blockIdx.x * 32;
    if (base >= N_NODES) return;
    int tid = threadIdx.x;
    int c = tid & 63;
    int rr = tid >> 6;
    int lastIdx = min(base + 31, N_NODES - 1);
    int b0 = batch[base];
    bool uniform = (batch[lastIdx] == b0);
    if (uniform) {
        float acc = 0.f;
        for (int r = rr; r < 32; r += 4) {
            int i = base + r;
            if (i < N_NODES) acc += h[(size_t)i * 64 + c];
        }
        red[rr][c] = acc;
        __syncthreads();
        if (rr == 0) {
            float sum = red[0][c] + red[1][c] + red[2][c] + red[3][c];
            atomicAdd(&g[b0 * 64 + c], sum);
        }
    } else {
        for (int r = rr; r < 32; r += 4) {
            int i = base + r;
            if (i < N_NODES) atomicAdd(&g[batch[i] * 64 + c], h[(size_t)i * 64 + c]);
        }
    }
}

// ---------------------------------------------------------------- head
__global__ void k_head(const float* __restrict__ g, const float* __restrict__ pw,
                       const float* __restrict__ pb, const float* __restrict__ cw,
                       const float* __restrict__ cb, float* __restrict__ out) {
    int gb = blockIdx.x;
    int c = threadIdx.x;
    const float* gr = g + gb * 64;
    float a = pb[c];
    const float* pwr = pw + c * 64;
#pragma unroll
    for (int k = 0; k < 64; k++) a += gr[k] * pwr[k];
    a = a > 0.f ? a : 0.f;
    float o0 = wave_sum(a * cw[c]);
    float o1 = wave_sum(a * cw[64 + c]);
    if (c == 0) {
        out[gb * 2 + 0] = o0 + cb[0];
        out[gb * 2 + 1] = o1 + cb[1];
    }
}

// ---------------------------------------------------------------- launcher
extern "C" void kernel_launch(void* const* d_in, const int* in_sizes, int n_in,
                              void* d_out, int out_size, void* d_ws, size_t ws_size,
                              hipStream_t stream) {
    const float* x    = (const float*)d_in[0];
    const int*   ei   = (const int*)d_in[1];
    const int*   bidx = (const int*)d_in[2];
    const float* wl1 = (const float*)d_in[3],  *bl1 = (const float*)d_in[4];
    const float* wr1 = (const float*)d_in[5],  *br1 = (const float*)d_in[6];
    const float* att1 = (const float*)d_in[7], *bo1 = (const float*)d_in[8];
    const float* wl2 = (const float*)d_in[9],  *bl2 = (const float*)d_in[10];
    const float* wr2 = (const float*)d_in[11], *br2 = (const float*)d_in[12];
    const float* att2 = (const float*)d_in[13], *bo2 = (const float*)d_in[14];
    const float* wl3 = (const float*)d_in[15], *bl3 = (const float*)d_in[16];
    const float* wr3 = (const float*)d_in[17], *br3 = (const float*)d_in[18];
    const float* att3 = (const float*)d_in[19], *bo3 = (const float*)d_in[20];
    const float* lw = (const float*)d_in[21], *lb = (const float*)d_in[22];
    const float* pw = (const float*)d_in[23], *pb = (const float*)d_in[24];
    const float* cw = (const float*)d_in[25], *cb = (const float*)d_in[26];
    float* out = (float*)d_out;

    char* wsb = (char*)d_ws;
    size_t off = 0;
    auto alloc = [&](size_t bytes) {
        void* p = wsb + off;
        off = (off + bytes + 255) & ~(size_t)255;
        return p;
    };
    int* cnt      = (int*)alloc((size_t)N_NODES * 4);
    int* rowptr   = (int*)alloc((size_t)(N_NODES + 1) * 4);
    int* cursor   = (int*)alloc((size_t)N_NODES * 4);
    int* blocksum = (int*)alloc((size_t)SCAN_NB * 4);
    int* bcnt     = (int*)alloc((size_t)NBUCK * 4);
    int2* stage   = (int2*)alloc((size_t)NBUCK * BCAP * 8);
    int* csr_src  = (int*)alloc((size_t)N_EDGES * 4);
    const int woff[8] = {0, 8192, 16384, 20480, 24576, 28672, 32768, 45056};
    ushort_t* whi = (ushort_t*)alloc((size_t)45056 * 2);
    ushort_t* wlo = (ushort_t*)alloc((size_t)45056 * 2);
    ushort_t* xl   = (ushort_t*)alloc((size_t)N_NODES * 64 * 2);
    ushort_t* xrr  = (ushort_t*)alloc((size_t)N_NODES * 64 * 2);
    ushort_t* x1b  = (ushort_t*)alloc((size_t)N_NODES * 64 * 2);
    ushort_t* x2b  = (ushort_t*)alloc((size_t)N_NODES * 64 * 2);
    ushort_t* x3b  = (ushort_t*)alloc((size_t)N_NODES * 64 * 2);
    float* hb     = (float*)alloc((size_t)N_NODES * 64 * 4);
    float* g      = (float*)alloc((size_t)NGRAPH * 64 * 4);
    (void)ws_size; (void)in_sizes; (void)n_in; (void)out_size;

    const int* srcp = ei;
    const int* dstp = ei + N_EDGES;

    hipMemsetAsync(bcnt, 0, (size_t)NBUCK * 4, stream);
    hipMemsetAsync(g, 0, (size_t)NGRAPH * 64 * 4, stream);

    k_bucket<<<ABLK, 256, 0, stream>>>(srcp, dstp, bcnt, stage);
    k_hist2<<<NBUCK, 256, 0, stream>>>(bcnt, stage, cnt);
    k_scan1<<<SCAN_NB, 1024, 0, stream>>>(cnt, rowptr, blocksum);
    k_scan2<<<1, 64, 0, stream>>>(blocksum);
    k_scan3<<<SCAN_NB, 1024, 0, stream>>>(rowptr, blocksum, cursor);
    k_scatter2<<<NBUCK, 256, 0, stream>>>(bcnt, stage, cursor, csr_src);

    WSrc ws;
    ws.s[0] = wl1; ws.s[1] = wr1; ws.s[2] = wl2; ws.s[3] = wr2;
    ws.s[4] = wl3; ws.s[5] = wr3; ws.s[6] = lw;
    for (int i = 0; i < 8; i++) ws.off[i] = woff[i];
    k_cvt_w<<<64, 256, 0, stream>>>(ws, whi, wlo);

    int gemmBlocks = (N_NODES + 63) / 64;
    int gatBlocks = (N_NODES + 3) / 4;

    // layer 1
    k_gemm_dual_mfma<128, true><<<gemmBlocks, 256, 0, stream>>>(
        x, whi + woff[0], wlo + woff[0], whi + woff[1], wlo + woff[1], bl1, br1, xl, xrr);
    k_gat<<<gatBlocks, 256, 0, stream>>>(xl, xrr, rowptr, csr_src, att1, bo1, x1b);
    // layer 2
    k_gemm_dual_mfma<64, false><<<gemmBlocks, 256, 0, stream>>>(
        x1b, whi + woff[2], wlo + woff[2], whi + woff[3], wlo + woff[3], bl2, br2, xl, xrr);
    k_gat<<<gatBlocks, 256, 0, stream>>>(xl, xrr, rowptr, csr_src, att2, bo2, x2b);
    // layer 3
    k_gemm_dual_mfma<64, false><<<gemmBlocks, 256, 0, stream>>>(
        x2b, whi + woff[4], wlo + woff[4], whi + woff[5], wlo + woff[5], bl3, br3, xl, xrr);
    k_gat<<<gatBlocks, 256, 0, stream>>>(xl, xrr, rowptr, csr_src, att3, bo3, x3b);

    // head
    k_gemm_h_mfma<<<gemmBlocks, 256, 0, stream>>>(x1b, x2b, x3b, whi + woff[6], wlo + woff[6], lb, hb);
    k_pool<<<(N_NODES + 31) / 32, 256, 0, stream>>>(hb, bidx, g);
    k_head<<<NGRAPH, 64, 0, stream>>>(g, pw, pb, cw, cb, out);
}

// Round 8
// 315.753 us; speedup vs baseline: 1.4310x; 1.0694x over previous
//
#include <hip/hip_runtime.h>
#include <hip/hip_bf16.h>

#define N_NODES 50000
#define N_EDGES 800000
#define FDIM 128
#define CDIM 64
#define NGRAPH 256
#define LRELU_SLOPE 0.2f
#define SCAN_NB ((N_NODES + 1023) / 1024)   // 49
#define NBUCK ((N_NODES + 255) / 256)       // 196 buckets of 256 nodes
#define BCAP 5120                            // stage capacity/bucket (mean 4082, 16 sigma)
#define ABLK 400                             // pass-A blocks
#define EPB ((N_EDGES + ABLK - 1) / ABLK)    // 2000 edges per pass-A block

typedef unsigned short ushort_t;
typedef unsigned int uint_t;
typedef __attribute__((ext_vector_type(8))) short short8v;
typedef __attribute__((ext_vector_type(4))) float float4v;

// ---------------------------------------------------------------- bf16 helpers (RNE)
__device__ __forceinline__ ushort_t f2bf(float f) {
    uint_t u = __float_as_uint(f);
    u += 0x7FFFu + ((u >> 16) & 1u);
    return (ushort_t)(u >> 16);
}
__device__ __forceinline__ float bf2f(ushort_t u) {
    return __uint_as_float(((uint_t)u) << 16);
}

// single v_exp_f32 (computes 2^x natively on gfx950)
__device__ __forceinline__ float fast_exp2(float x) {
    return __builtin_amdgcn_exp2f(x);
}

__device__ __forceinline__ float wave_sum(float v) {
#pragma unroll
    for (int off = 32; off >= 1; off >>= 1) v += __shfl_xor(v, off);
    return v;
}

__device__ __forceinline__ int wave_incl_scan(int v, int lane) {
#pragma unroll
    for (int off = 1; off < 64; off <<= 1) {
        int t = __shfl_up(v, off);
        if (lane >= off) v += t;
    }
    return v;
}

// ---------------------------------------------------------------- CSR build, locality 2-pass
__global__ void k_bucket(const int* __restrict__ src, const int* __restrict__ dst,
                         int* __restrict__ bcnt, int2* __restrict__ stage) {
    __shared__ int lhist[NBUCK];
    __shared__ int lbase[NBUCK];
    __shared__ int lcur[NBUCK];
    int tid = threadIdx.x;
    int e0 = blockIdx.x * EPB;
    int e1 = min(e0 + EPB, N_EDGES);
    for (int t = tid; t < NBUCK; t += 256) { lhist[t] = 0; lcur[t] = 0; }
    __syncthreads();
    for (int e = e0 + tid; e < e1; e += 256)
        atomicAdd(&lhist[dst[e] >> 8], 1);
    __syncthreads();
    for (int t = tid; t < NBUCK; t += 256)
        lbase[t] = atomicAdd(&bcnt[t], lhist[t]);
    __syncthreads();
    for (int e = e0 + tid; e < e1; e += 256) {
        int s = src[e], d = dst[e];
        int b = d >> 8;
        int loff = atomicAdd(&lcur[b], 1);
        int pos = lbase[b] + loff;
        if (pos < BCAP) stage[(size_t)b * BCAP + pos] = make_int2(s, d);
    }
}

__global__ void k_hist2(const int* __restrict__ bcnt, const int2* __restrict__ stage,
                        int* __restrict__ cnt) {
    __shared__ int lcnt[256];
    int b = blockIdx.x;
    int tid = threadIdx.x;
    lcnt[tid] = 0;
    __syncthreads();
    int n = min(bcnt[b], BCAP);
    const int2* sp = stage + (size_t)b * BCAP;
    for (int i = tid; i < n; i += 256)
        atomicAdd(&lcnt[sp[i].y & 255], 1);
    __syncthreads();
    int node = (b << 8) + tid;
    if (node < N_NODES) cnt[node] = lcnt[tid];
}

__global__ void k_scan1(const int* __restrict__ cnt, int* __restrict__ rowptr,
                        int* __restrict__ blocksum) {
    __shared__ int wsum[16];
    int tid = threadIdx.x;
    int gid = blockIdx.x * 1024 + tid;
    int lane = tid & 63, wid = tid >> 6;
    int v = (gid < N_NODES) ? cnt[gid] : 0;
    int incl = wave_incl_scan(v, lane);
    if (lane == 63) wsum[wid] = incl;
    __syncthreads();
    if (wid == 0) {
        int wv = (lane < 16) ? wsum[lane] : 0;
        int wincl = wave_incl_scan(wv, lane);
        if (lane < 16) wsum[lane] = wincl - wv;
    }
    __syncthreads();
    int excl = incl - v + wsum[wid];
    if (gid < N_NODES) rowptr[gid] = excl;
    if (tid == 1023) blocksum[blockIdx.x] = excl + v;
}

__global__ void k_scan2(int* __restrict__ blocksum) {
    int lane = threadIdx.x;
    int v = (lane < SCAN_NB) ? blocksum[lane] : 0;
    int incl = wave_incl_scan(v, lane);
    if (lane < SCAN_NB) blocksum[lane] = incl - v;
}

__global__ void k_scan3(int* __restrict__ rowptr, const int* __restrict__ blocksum,
                        int* __restrict__ cursor) {
    int tid = threadIdx.x;
    int gid = blockIdx.x * 1024 + tid;
    if (gid < N_NODES) {
        int r = rowptr[gid] + blocksum[blockIdx.x];
        rowptr[gid] = r;
        cursor[gid] = r;
    }
    if (blockIdx.x == 0 && tid == 0) rowptr[N_NODES] = N_EDGES;
}

__global__ void k_scatter2(const int* __restrict__ bcnt, const int2* __restrict__ stage,
                           int* __restrict__ cursor, int* __restrict__ csr_src) {
    int b = blockIdx.x;
    int tid = threadIdx.x;
    int n = min(bcnt[b], BCAP);
    const int2* sp = stage + (size_t)b * BCAP;
    for (int i = tid; i < n; i += 256) {
        int2 sd = sp[i];
        int pos = atomicAdd(&cursor[sd.y], 1);
        csr_src[pos] = sd.x;
    }
}

// ---------------------------------------------------------------- weight f32 -> hi/lo bf16
struct WSrc {
    const float* s[7];
    int off[8];
};
__global__ void k_cvt_w(WSrc ws, ushort_t* __restrict__ hi, ushort_t* __restrict__ lo) {
    int gid = blockIdx.x * 256 + threadIdx.x;
    int stride = gridDim.x * 256;
#pragma unroll
    for (int mi = 0; mi < 7; mi++) {
        int n = ws.off[mi + 1] - ws.off[mi];
        const float* s = ws.s[mi];
        ushort_t* h = hi + ws.off[mi];
        ushort_t* l = lo + ws.off[mi];
        for (int i = gid; i < n; i += stride) {
            float f = s[i];
            ushort_t hb = f2bf(f);
            h[i] = hb;
            l[i] = f2bf(f - bf2f(hb));
        }
    }
}

// ---------------------------------------------------------------- dual projection via MFMA
template <int K, bool A_FP32>
__global__ void k_gemm_dual_mfma(const void* __restrict__ xa,
                                 const ushort_t* __restrict__ wlh, const ushort_t* __restrict__ wll,
                                 const ushort_t* __restrict__ wrh, const ushort_t* __restrict__ wrl,
                                 const float* __restrict__ bl, const float* __restrict__ br,
                                 ushort_t* __restrict__ xl, ushort_t* __restrict__ xr) {
    int tid = threadIdx.x;
    int wv = tid >> 6, lane = tid & 63;
    int m0 = blockIdx.x * 64 + wv * 16;
    if (m0 >= N_NODES) return;
    int arow = min(m0 + (lane & 15), N_NODES - 1);
    int koff = (lane >> 4) * 8;
    int wrow = lane & 15;

    float4v acc[8];
#pragma unroll
    for (int f = 0; f < 8; f++) acc[f] = (float4v)(0.f);

#pragma unroll
    for (int k0 = 0; k0 < K; k0 += 32) {
        short8v afrag;
        if (A_FP32) {
            const float* ap = (const float*)xa + (size_t)arow * K + k0 + koff;
            float4 a0 = *reinterpret_cast<const float4*>(ap);
            float4 a1 = *reinterpret_cast<const float4*>(ap + 4);
            afrag[0] = (short)f2bf(a0.x); afrag[1] = (short)f2bf(a0.y);
            afrag[2] = (short)f2bf(a0.z); afrag[3] = (short)f2bf(a0.w);
            afrag[4] = (short)f2bf(a1.x); afrag[5] = (short)f2bf(a1.y);
            afrag[6] = (short)f2bf(a1.z); afrag[7] = (short)f2bf(a1.w);
        } else {
            afrag = *reinterpret_cast<const short8v*>((const ushort_t*)xa + (size_t)arow * K + k0 + koff);
        }
#pragma unroll
        for (int f = 0; f < 8; f++) {
            const ushort_t* bh = (f < 4) ? wlh : wrh;
            const ushort_t* blo = (f < 4) ? wll : wrl;
            int row = ((f * 16 + wrow) & 63);
            size_t boff = (size_t)row * K + k0 + koff;
            short8v bfh = *reinterpret_cast<const short8v*>(bh + boff);
            short8v bfl = *reinterpret_cast<const short8v*>(blo + boff);
            acc[f] = __builtin_amdgcn_mfma_f32_16x16x32_bf16(afrag, bfh, acc[f], 0, 0, 0);
            acc[f] = __builtin_amdgcn_mfma_f32_16x16x32_bf16(afrag, bfl, acc[f], 0, 0, 0);
        }
    }

    int r0 = m0 + (lane >> 4) * 4;
#pragma unroll
    for (int f = 0; f < 8; f++) {
        int col = f * 16 + (lane & 15);
        float bias = (col < 64) ? bl[col] : br[col - 64];
        ushort_t* dstp = (col < 64) ? xl : xr;
        int c = col & 63;
#pragma unroll
        for (int j = 0; j < 4; j++) {
            int row = r0 + j;
            if (row < N_NODES) dstp[(size_t)row * 64 + c] = f2bf(acc[f][j] + bias);
        }
    }
}

// ---------------------------------------------------------------- h = relu(concat @ lin1_w.T + b)
__global__ void k_gemm_h_mfma(const ushort_t* __restrict__ x1, const ushort_t* __restrict__ x2,
                              const ushort_t* __restrict__ x3,
                              const ushort_t* __restrict__ whi, const ushort_t* __restrict__ wlo,
                              const float* __restrict__ b, float* __restrict__ h) {
    int tid = threadIdx.x;
    int wv = tid >> 6, lane = tid & 63;
    int m0 = blockIdx.x * 64 + wv * 16;
    if (m0 >= N_NODES) return;
    int arow = min(m0 + (lane & 15), N_NODES - 1);
    int koff = (lane >> 4) * 8;
    int wrow = lane & 15;

    float4v acc[4];
#pragma unroll
    for (int f = 0; f < 4; f++) acc[f] = (float4v)(0.f);

#pragma unroll
    for (int ks = 0; ks < 6; ks++) {
        int k0 = ks * 32;
        const ushort_t* srcp = (ks < 2) ? x1 : (ks < 4 ? x2 : x3);
        int kc = k0 & 63;
        short8v afrag = *reinterpret_cast<const short8v*>(srcp + (size_t)arow * 64 + kc + koff);
#pragma unroll
        for (int f = 0; f < 4; f++) {
            size_t boff = (size_t)(f * 16 + wrow) * 192 + k0 + koff;
            short8v bfh = *reinterpret_cast<const short8v*>(whi + boff);
            short8v bfl = *reinterpret_cast<const short8v*>(wlo + boff);
            acc[f] = __builtin_amdgcn_mfma_f32_16x16x32_bf16(afrag, bfh, acc[f], 0, 0, 0);
            acc[f] = __builtin_amdgcn_mfma_f32_16x16x32_bf16(afrag, bfl, acc[f], 0, 0, 0);
        }
    }

    int r0 = m0 + (lane >> 4) * 4;
#pragma unroll
    for (int f = 0; f < 4; f++) {
        int col = f * 16 + (lane & 15);
        float bias = b[col];
#pragma unroll
        for (int j = 0; j < 4; j++) {
            int row = r0 + j;
            if (row < N_NODES) {
                float o = acc[f][j] + bias;
                h[(size_t)row * 64 + col] = o > 0.f ? o : 0.f;
            }
        }
    }
}

// ---------------------------------------------------------------- GATv2 aggregate: one wave per dst node
// fused online softmax in log2 domain; max-form lrelu; skip-rescale; 8-edge unroll
__global__ void k_gat(const ushort_t* __restrict__ xl, const ushort_t* __restrict__ xr,
                      const int* __restrict__ rowptr, const int* __restrict__ csr_src,
                      const float* __restrict__ att, const float* __restrict__ bo,
                      ushort_t* __restrict__ xout) {
    int wid = blockIdx.x * 4 + (threadIdx.x >> 6);
    int lane = threadIdx.x & 63;
    if (wid >= N_NODES) return;
    const float LOG2E = 1.44269504f;
    float attv = att[lane] * LOG2E;      // log2-domain scores
    float xrv = bf2f(xr[(size_t)wid * 64 + lane]);
    float xls = bf2f(xl[(size_t)wid * 64 + lane]);
    int beg = rowptr[wid], end = rowptr[wid + 1];

    float s = xls + xrv;
    float t = fmaxf(s, LRELU_SLOPE * s) * attv;   // lrelu(s) == max(s, 0.2s)
    float m = wave_sum(t);
    float ssum = 1.0f;
    float acc = xls;

    bool b0 = (lane & 1) != 0;
    bool b1 = (lane & 2) != 0;

    // class tree: fold 4 edges into lane classes, butterfly, broadcast
    auto tree = [&](float t0, float t1, float t2, float t3,
                    float& f0, float& f1, float& f2, float& f3) {
        float c = (b0 ? t1 : t0) + __shfl_xor(b0 ? t0 : t1, 1);
        float d = (b0 ? t3 : t2) + __shfl_xor(b0 ? t2 : t3, 1);
        float e = (b1 ? d : c) + __shfl_xor(b1 ? c : d, 2);
        e += __shfl_xor(e, 4);
        e += __shfl_xor(e, 8);
        e += __shfl_xor(e, 16);
        e += __shfl_xor(e, 32);
        f0 = e;
        f1 = __shfl_xor(e, 1);
        f2 = __shfl_xor(e, 2);
        f3 = __shfl_xor(f2, 1);
    };
    // permute gathered features so w_k pairs with its edge (class c^k ordering)
    auto perm = [&](float v0, float v1, float v2, float v3,
                    float& p0, float& p1, float& p2, float& p3) {
        float x01 = b0 ? v1 : v0, x01b = b0 ? v0 : v1;
        float x23 = b0 ? v3 : v2, x23b = b0 ? v2 : v3;
        p0 = b1 ? x23 : x01;  p2 = b1 ? x01 : x23;
        p1 = b1 ? x23b : x01b; p3 = b1 ? x01b : x23b;
    };

    int j = beg;
    for (; j + 8 <= end; j += 8) {
        int s0 = csr_src[j + 0], s1 = csr_src[j + 1];
        int s2 = csr_src[j + 2], s3 = csr_src[j + 3];
        int s4 = csr_src[j + 4], s5 = csr_src[j + 5];
        int s6 = csr_src[j + 6], s7 = csr_src[j + 7];
        float v0 = bf2f(xl[(size_t)s0 * 64 + lane]);
        float v1 = bf2f(xl[(size_t)s1 * 64 + lane]);
        float v2 = bf2f(xl[(size_t)s2 * 64 + lane]);
        float v3 = bf2f(xl[(size_t)s3 * 64 + lane]);
        float v4 = bf2f(xl[(size_t)s4 * 64 + lane]);
        float v5 = bf2f(xl[(size_t)s5 * 64 + lane]);
        float v6 = bf2f(xl[(size_t)s6 * 64 + lane]);
        float v7 = bf2f(xl[(size_t)s7 * 64 + lane]);
        float a0 = v0 + xrv, a1 = v1 + xrv, a2 = v2 + xrv, a3 = v3 + xrv;
        float a4 = v4 + xrv, a5 = v5 + xrv, a6 = v6 + xrv, a7 = v7 + xrv;
        float t0 = fmaxf(a0, LRELU_SLOPE * a0) * attv;
        float t1 = fmaxf(a1, LRELU_SLOPE * a1) * attv;
        float t2 = fmaxf(a2, LRELU_SLOPE * a2) * attv;
        float t3 = fmaxf(a3, LRELU_SLOPE * a3) * attv;
        float t4 = fmaxf(a4, LRELU_SLOPE * a4) * attv;
        float t5 = fmaxf(a5, LRELU_SLOPE * a5) * attv;
        float t6 = fmaxf(a6, LRELU_SLOPE * a6) * attv;
        float t7 = fmaxf(a7, LRELU_SLOPE * a7) * attv;

        float fA0, fA1, fA2, fA3, fB0, fB1, fB2, fB3;
        tree(t0, t1, t2, t3, fA0, fA1, fA2, fA3);
        tree(t4, t5, t6, t7, fB0, fB1, fB2, fB3);

        float mxA = fmaxf(fmaxf(fA0, fA1), fmaxf(fA2, fA3));
        float mxB = fmaxf(fmaxf(fB0, fB1), fmaxf(fB2, fB3));
        float mn = fmaxf(m, fmaxf(mxA, mxB));
        if (mn > m) {              // wave-uniform branch (rare)
            float sc = fast_exp2(m - mn);
            ssum *= sc;
            acc *= sc;
            m = mn;
        }
        float wA0 = fast_exp2(fA0 - m), wA1 = fast_exp2(fA1 - m);
        float wA2 = fast_exp2(fA2 - m), wA3 = fast_exp2(fA3 - m);
        float wB0 = fast_exp2(fB0 - m), wB1 = fast_exp2(fB1 - m);
        float wB2 = fast_exp2(fB2 - m), wB3 = fast_exp2(fB3 - m);
        ssum += ((wA0 + wA1) + (wA2 + wA3)) + ((wB0 + wB1) + (wB2 + wB3));

        float pA0, pA1, pA2, pA3, pB0, pB1, pB2, pB3;
        perm(v0, v1, v2, v3, pA0, pA1, pA2, pA3);
        perm(v4, v5, v6, v7, pB0, pB1, pB2, pB3);
        acc += ((wA0 * pA0 + wA1 * pA1) + (wA2 * pA2 + wA3 * pA3)) +
               ((wB0 * pB0 + wB1 * pB1) + (wB2 * pB2 + wB3 * pB3));
    }
    for (; j + 4 <= end; j += 4) {
        int s0 = csr_src[j + 0], s1 = csr_src[j + 1];
        int s2 = csr_src[j + 2], s3 = csr_src[j + 3];
        float v0 = bf2f(xl[(size_t)s0 * 64 + lane]);
        float v1 = bf2f(xl[(size_t)s1 * 64 + lane]);
        float v2 = bf2f(xl[(size_t)s2 * 64 + lane]);
        float v3 = bf2f(xl[(size_t)s3 * 64 + lane]);
        float a0 = v0 + xrv, a1 = v1 + xrv, a2 = v2 + xrv, a3 = v3 + xrv;
        float t0 = fmaxf(a0, LRELU_SLOPE * a0) * attv;
        float t1 = fmaxf(a1, LRELU_SLOPE * a1) * attv;
        float t2 = fmaxf(a2, LRELU_SLOPE * a2) * attv;
        float t3 = fmaxf(a3, LRELU_SLOPE * a3) * attv;
        float f0, f1, f2, f3;
        tree(t0, t1, t2, t3, f0, f1, f2, f3);
        float mn = fmaxf(fmaxf(fmaxf(f0, f1), fmaxf(f2, f3)), m);
        if (mn > m) {
            float sc = fast_exp2(m - mn);
            ssum *= sc;
            acc *= sc;
            m = mn;
        }
        float w0 = fast_exp2(f0 - m), w1 = fast_exp2(f1 - m);
        float w2 = fast_exp2(f2 - m), w3 = fast_exp2(f3 - m);
        ssum += (w0 + w1) + (w2 + w3);
        float p0, p1, p2, p3;
        perm(v0, v1, v2, v3, p0, p1, p2, p3);
        acc += (w0 * p0 + w1 * p1) + (w2 * p2 + w3 * p3);
    }
    for (; j < end; j++) {
        int sj = csr_src[j];
        float v = bf2f(xl[(size_t)sj * 64 + lane]);
        float a = v + xrv;
        float tt = fmaxf(a, LRELU_SLOPE * a) * attv;
        float e = wave_sum(tt);
        float mn = fmaxf(m, e);
        if (mn > m) {
            float sc = fast_exp2(m - mn);
            ssum *= sc;
            acc *= sc;
            m = mn;
        }
        float w = fast_exp2(e - m);
        ssum += w;
        acc += w * v;
    }

    float o = acc / (ssum + 1e-16f) + bo[lane];
    xout[(size_t)wid * 64 + lane] = f2bf(o > 0.f ? o : 0.f);
}

// ---------------------------------------------------------------- global_add_pool (batch_idx sorted)
__global__ void k_pool(const float* __restrict__ h, const int* __restrict__ batch,
                       float* __restrict__ g) {
    __shared__ float red[4][64];
    int base = blockIdx.x * 32;
    if (base >= N_NODES) return;
    int tid = threadIdx.x;
    int c = tid & 63;
    int rr = tid >> 6;
    int lastIdx = min(base + 31, N_NODES - 1);
    int b0 = batch[base];
    bool uniform = (batch[lastIdx] == b0);
    if (uniform) {
        float acc = 0.f;
        for (int r = rr; r < 32; r += 4) {
            int i = base + r;
            if (i < N_NODES) acc += h[(size_t)i * 64 + c];
        }
        red[rr][c] = acc;
        __syncthreads();
        if (rr == 0) {
            float sum = red[0][c] + red[1][c] + red[2][c] + red[3][c];
            atomicAdd(&g[b0 * 64 + c], sum);
        }
    } else {
        for (int r = rr; r < 32; r += 4) {
            int i = base + r;
            if (i < N_NODES) atomicAdd(&g[batch[i] * 64 + c], h[(size_t)i * 64 + c]);
        }
    }
}

// ---------------------------------------------------------------- head
__global__ void k_head(const float* __restrict__ g, const float* __restrict__ pw,
                       const float* __restrict__ pb, const float* __restrict__ cw,
                       const float* __restrict__ cb, float* __restrict__ out) {
    int gb = blockIdx.x;
    int c = threadIdx.x;
    const float* gr = g + gb * 64;
    float a = pb[c];
    const float* pwr = pw + c * 64;
#pragma unroll
    for (int k = 0; k < 64; k++) a += gr[k] * pwr[k];
    a = a > 0.f ? a : 0.f;
    float o0 = wave_sum(a * cw[c]);
    float o1 = wave_sum(a * cw[64 + c]);
    if (c == 0) {
        out[gb * 2 + 0] = o0 + cb[0];
        out[gb * 2 + 1] = o1 + cb[1];
    }
}

// ---------------------------------------------------------------- launcher
extern "C" void kernel_launch(void* const* d_in, const int* in_sizes, int n_in,
                              void* d_out, int out_size, void* d_ws, size_t ws_size,
                              hipStream_t stream) {
    const float* x    = (const float*)d_in[0];
    const int*   ei   = (const int*)d_in[1];
    const int*   bidx = (const int*)d_in[2];
    const float* wl1 = (const float*)d_in[3],  *bl1 = (const float*)d_in[4];
    const float* wr1 = (const float*)d_in[5],  *br1 = (const float*)d_in[6];
    const float* att1 = (const float*)d_in[7], *bo1 = (const float*)d_in[8];
    const float* wl2 = (const float*)d_in[9],  *bl2 = (const float*)d_in[10];
    const float* wr2 = (const float*)d_in[11], *br2 = (const float*)d_in[12];
    const float* att2 = (const float*)d_in[13], *bo2 = (const float*)d_in[14];
    const float* wl3 = (const float*)d_in[15], *bl3 = (const float*)d_in[16];
    const float* wr3 = (const float*)d_in[17], *br3 = (const float*)d_in[18];
    const float* att3 = (const float*)d_in[19], *bo3 = (const float*)d_in[20];
    const float* lw = (const float*)d_in[21], *lb = (const float*)d_in[22];
    const float* pw = (const float*)d_in[23], *pb = (const float*)d_in[24];
    const float* cw = (const float*)d_in[25], *cb = (const float*)d_in[26];
    float* out = (float*)d_out;

    char* wsb = (char*)d_ws;
    size_t off = 0;
    auto alloc = [&](size_t bytes) {
        void* p = wsb + off;
        off = (off + bytes + 255) & ~(size_t)255;
        return p;
    };
    int* cnt      = (int*)alloc((size_t)N_NODES * 4);
    int* rowptr   = (int*)alloc((size_t)(N_NODES + 1) * 4);
    int* cursor   = (int*)alloc((size_t)N_NODES * 4);
    int* blocksum = (int*)alloc((size_t)SCAN_NB * 4);
    int* bcnt     = (int*)alloc((size_t)NBUCK * 4);
    int2* stage   = (int2*)alloc((size_t)NBUCK * BCAP * 8);
    int* csr_src  = (int*)alloc((size_t)N_EDGES * 4);
    const int woff[8] = {0, 8192, 16384, 20480, 24576, 28672, 32768, 45056};
    ushort_t* whi = (ushort_t*)alloc((size_t)45056 * 2);
    ushort_t* wlo = (ushort_t*)alloc((size_t)45056 * 2);
    ushort_t* xl   = (ushort_t*)alloc((size_t)N_NODES * 64 * 2);
    ushort_t* xrr  = (ushort_t*)alloc((size_t)N_NODES * 64 * 2);
    ushort_t* x1b  = (ushort_t*)alloc((size_t)N_NODES * 64 * 2);
    ushort_t* x2b  = (ushort_t*)alloc((size_t)N_NODES * 64 * 2);
    ushort_t* x3b  = (ushort_t*)alloc((size_t)N_NODES * 64 * 2);
    float* hb     = (float*)alloc((size_t)N_NODES * 64 * 4);
    float* g      = (float*)alloc((size_t)NGRAPH * 64 * 4);
    (void)ws_size; (void)in_sizes; (void)n_in; (void)out_size;

    const int* srcp = ei;
    const int* dstp = ei + N_EDGES;

    hipMemsetAsync(bcnt, 0, (size_t)NBUCK * 4, stream);
    hipMemsetAsync(g, 0, (size_t)NGRAPH * 64 * 4, stream);

    k_bucket<<<ABLK, 256, 0, stream>>>(srcp, dstp, bcnt, stage);
    k_hist2<<<NBUCK, 256, 0, stream>>>(bcnt, stage, cnt);
    k_scan1<<<SCAN_NB, 1024, 0, stream>>>(cnt, rowptr, blocksum);
    k_scan2<<<1, 64, 0, stream>>>(blocksum);
    k_scan3<<<SCAN_NB, 1024, 0, stream>>>(rowptr, blocksum, cursor);
    k_scatter2<<<NBUCK, 256, 0, stream>>>(bcnt, stage, cursor, csr_src);

    WSrc ws;
    ws.s[0] = wl1; ws.s[1] = wr1; ws.s[2] = wl2; ws.s[3] = wr2;
    ws.s[4] = wl3; ws.s[5] = wr3; ws.s[6] = lw;
    for (int i = 0; i < 8; i++) ws.off[i] = woff[i];
    k_cvt_w<<<64, 256, 0, stream>>>(ws, whi, wlo);

    int gemmBlocks = (N_NODES + 63) / 64;
    int gatBlocks = (N_NODES + 3) / 4;

    // layer 1
    k_gemm_dual_mfma<128, true><<<gemmBlocks, 256, 0, stream>>>(
        x, whi + woff[0], wlo + woff[0], whi + woff[1], wlo + woff[1], bl1, br1, xl, xrr);
    k_gat<<<gatBlocks, 256, 0, stream>>>(xl, xrr, rowptr, csr_src, att1, bo1, x1b);
    // layer 2
    k_gemm_dual_mfma<64, false><<<gemmBlocks, 256, 0, stream>>>(
        x1b, whi + woff[2], wlo + woff[2], whi + woff[3], wlo + woff[3], bl2, br2, xl, xrr);
    k_gat<<<gatBlocks, 256, 0, stream>>>(xl, xrr, rowptr, csr_src, att2, bo2, x2b);
    // layer 3
    k_gemm_dual_mfma<64, false><<<gemmBlocks, 256, 0, stream>>>(
        x2b, whi + woff[4], wlo + woff[4], whi + woff[5], wlo + woff[5], bl3, br3, xl, xrr);
    k_gat<<<gatBlocks, 256, 0, stream>>>(xl, xrr, rowptr, csr_src, att3, bo3, x3b);

    // head
    k_gemm_h_mfma<<<gemmBlocks, 256, 0, stream>>>(x1b, x2b, x3b, whi + woff[6], wlo + woff[6], lb, hb);
    k_pool<<<(N_NODES + 31) / 32, 256, 0, stream>>>(hb, bidx, g);
    k_head<<<NGRAPH, 64, 0, stream>>>(g, pw, pb, cw, cb, out);
}

// Round 9
// 262.886 us; speedup vs baseline: 1.7188x; 1.2011x over previous
//
#include <hip/hip_runtime.h>
#include <hip/hip_bf16.h>

#define N_NODES 50000
#define N_EDGES 800000
#define FDIM 128
#define CDIM 64
#define NGRAPH 256
#define LRELU_SLOPE 0.2f
#define SCAN_NB ((N_NODES + 1023) / 1024)   // 49
#define NBUCK ((N_NODES + 255) / 256)       // 196 buckets of 256 nodes
#define BCAP 5120                            // stage capacity/bucket
#define ABLK 400                             // pass-A blocks
#define EPB ((N_EDGES + ABLK - 1) / ABLK)    // 2000 edges per pass-A block
#define NDBIN 64                             // degree bins for node ordering

typedef unsigned short ushort_t;
typedef unsigned int uint_t;
typedef __attribute__((ext_vector_type(8))) short short8v;
typedef __attribute__((ext_vector_type(4))) float float4v;

// ---------------------------------------------------------------- bf16 helpers (RNE)
__device__ __forceinline__ ushort_t f2bf(float f) {
    uint_t u = __float_as_uint(f);
    u += 0x7FFFu + ((u >> 16) & 1u);
    return (ushort_t)(u >> 16);
}
__device__ __forceinline__ float bf2f(ushort_t u) {
    return __uint_as_float(((uint_t)u) << 16);
}

// single v_exp_f32 (2^x native)
__device__ __forceinline__ float fast_exp2(float x) {
    return __builtin_amdgcn_exp2f(x);
}

__device__ __forceinline__ int wave_incl_scan(int v, int lane) {
#pragma unroll
    for (int off = 1; off < 64; off <<= 1) {
        int t = __shfl_up(v, off);
        if (lane >= off) v += t;
    }
    return v;
}

__device__ __forceinline__ float wave_sum(float v) {
#pragma unroll
    for (int off = 32; off >= 1; off >>= 1) v += __shfl_xor(v, off);
    return v;
}

// ---------------------------------------------------------------- CSR build, locality 2-pass
__global__ void k_bucket(const int* __restrict__ src, const int* __restrict__ dst,
                         int* __restrict__ bcnt, int2* __restrict__ stage) {
    __shared__ int lhist[NBUCK];
    __shared__ int lbase[NBUCK];
    __shared__ int lcur[NBUCK];
    int tid = threadIdx.x;
    int e0 = blockIdx.x * EPB;
    int e1 = min(e0 + EPB, N_EDGES);
    for (int t = tid; t < NBUCK; t += 256) { lhist[t] = 0; lcur[t] = 0; }
    __syncthreads();
    for (int e = e0 + tid; e < e1; e += 256)
        atomicAdd(&lhist[dst[e] >> 8], 1);
    __syncthreads();
    for (int t = tid; t < NBUCK; t += 256)
        lbase[t] = atomicAdd(&bcnt[t], lhist[t]);
    __syncthreads();
    for (int e = e0 + tid; e < e1; e += 256) {
        int s = src[e], d = dst[e];
        int b = d >> 8;
        int loff = atomicAdd(&lcur[b], 1);
        int pos = lbase[b] + loff;
        if (pos < BCAP) stage[(size_t)b * BCAP + pos] = make_int2(s, d);
    }
}

// per-bucket node histogram + global degree histogram
__global__ void k_hist2(const int* __restrict__ bcnt, const int2* __restrict__ stage,
                        int* __restrict__ cnt, int* __restrict__ dhist) {
    __shared__ int lcnt[256];
    __shared__ int ldh[NDBIN];
    int b = blockIdx.x;
    int tid = threadIdx.x;
    lcnt[tid] = 0;
    if (tid < NDBIN) ldh[tid] = 0;
    __syncthreads();
    int n = min(bcnt[b], BCAP);
    const int2* sp = stage + (size_t)b * BCAP;
    for (int i = tid; i < n; i += 256)
        atomicAdd(&lcnt[sp[i].y & 255], 1);
    __syncthreads();
    int node = (b << 8) + tid;
    if (node < N_NODES) {
        cnt[node] = lcnt[tid];
        atomicAdd(&ldh[min(lcnt[tid], NDBIN - 1)], 1);
    }
    __syncthreads();
    if (tid < NDBIN && ldh[tid]) atomicAdd(&dhist[tid], ldh[tid]);
}

__global__ void k_scan1(const int* __restrict__ cnt, int* __restrict__ rowptr,
                        int* __restrict__ blocksum) {
    __shared__ int wsum[16];
    int tid = threadIdx.x;
    int gid = blockIdx.x * 1024 + tid;
    int lane = tid & 63, wid = tid >> 6;
    int v = (gid < N_NODES) ? cnt[gid] : 0;
    int incl = wave_incl_scan(v, lane);
    if (lane == 63) wsum[wid] = incl;
    __syncthreads();
    if (wid == 0) {
        int wv = (lane < 16) ? wsum[lane] : 0;
        int wincl = wave_incl_scan(wv, lane);
        if (lane < 16) wsum[lane] = wincl - wv;
    }
    __syncthreads();
    int excl = incl - v + wsum[wid];
    if (gid < N_NODES) rowptr[gid] = excl;
    if (tid == 1023) blocksum[blockIdx.x] = excl + v;
}

// wave0: scan blocksums; wave1: scan degree hist -> dcur
__global__ void k_scan2(int* __restrict__ blocksum, const int* __restrict__ dhist,
                        int* __restrict__ dcur) {
    int tid = threadIdx.x;
    if (tid < 64) {
        int lane = tid;
        int v = (lane < SCAN_NB) ? blocksum[lane] : 0;
        int incl = wave_incl_scan(v, lane);
        if (lane < SCAN_NB) blocksum[lane] = incl - v;
    } else {
        int lane = tid - 64;
        int v = dhist[lane];
        int incl = wave_incl_scan(v, lane);
        dcur[lane] = incl - v;
    }
}

__global__ void k_scan3(int* __restrict__ rowptr, const int* __restrict__ blocksum,
                        int* __restrict__ cursor) {
    int tid = threadIdx.x;
    int gid = blockIdx.x * 1024 + tid;
    if (gid < N_NODES) {
        int r = rowptr[gid] + blocksum[blockIdx.x];
        rowptr[gid] = r;
        cursor[gid] = r;
    }
    if (blockIdx.x == 0 && tid == 0) rowptr[N_NODES] = N_EDGES;
}

__global__ void k_scatter2(const int* __restrict__ bcnt, const int2* __restrict__ stage,
                           int* __restrict__ cursor, int* __restrict__ csr_src) {
    int b = blockIdx.x;
    int tid = threadIdx.x;
    int n = min(bcnt[b], BCAP);
    const int2* sp = stage + (size_t)b * BCAP;
    for (int i = tid; i < n; i += 256) {
        int2 sd = sp[i];
        int pos = atomicAdd(&cursor[sd.y], 1);
        csr_src[pos] = sd.x;
    }
}

// degree-binned node ordering: order[] = nodes grouped by (clamped) degree
__global__ void k_dscatter(const int* __restrict__ cnt, int* __restrict__ dcur,
                           int* __restrict__ order) {
    __shared__ int lh[NDBIN], lb[NDBIN], lc[NDBIN];
    int b = blockIdx.x, tid = threadIdx.x;
    if (tid < NDBIN) { lh[tid] = 0; lc[tid] = 0; }
    __syncthreads();
    int node = b * 256 + tid;
    bool ok = node < N_NODES;
    int dg = ok ? min(cnt[node], NDBIN - 1) : 0;
    if (ok) atomicAdd(&lh[dg], 1);
    __syncthreads();
    if (tid < NDBIN) lb[tid] = lh[tid] ? atomicAdd(&dcur[tid], lh[tid]) : 0;
    __syncthreads();
    if (ok) {
        int off2 = atomicAdd(&lc[dg], 1);
        order[lb[dg] + off2] = node;
    }
}

// ---------------------------------------------------------------- weight f32 -> hi/lo bf16
struct WSrc {
    const float* s[7];
    int off[8];
};
__global__ void k_cvt_w(WSrc ws, ushort_t* __restrict__ hi, ushort_t* __restrict__ lo) {
    int gid = blockIdx.x * 256 + threadIdx.x;
    int stride = gridDim.x * 256;
#pragma unroll
    for (int mi = 0; mi < 7; mi++) {
        int n = ws.off[mi + 1] - ws.off[mi];
        const float* s = ws.s[mi];
        ushort_t* h = hi + ws.off[mi];
        ushort_t* l = lo + ws.off[mi];
        for (int i = gid; i < n; i += stride) {
            float f = s[i];
            ushort_t hb = f2bf(f);
            h[i] = hb;
            l[i] = f2bf(f - bf2f(hb));
        }
    }
}

// ---------------------------------------------------------------- dual projection via MFMA
template <int K, bool A_FP32>
__global__ void k_gemm_dual_mfma(const void* __restrict__ xa,
                                 const ushort_t* __restrict__ wlh, const ushort_t* __restrict__ wll,
                                 const ushort_t* __restrict__ wrh, const ushort_t* __restrict__ wrl,
                                 const float* __restrict__ bl, const float* __restrict__ br,
                                 ushort_t* __restrict__ xl, ushort_t* __restrict__ xr) {
    int tid = threadIdx.x;
    int wv = tid >> 6, lane = tid & 63;
    int m0 = blockIdx.x * 64 + wv * 16;
    if (m0 >= N_NODES) return;
    int arow = min(m0 + (lane & 15), N_NODES - 1);
    int koff = (lane >> 4) * 8;
    int wrow = lane & 15;

    float4v acc[8];
#pragma unroll
    for (int f = 0; f < 8; f++) acc[f] = (float4v)(0.f);

#pragma unroll
    for (int k0 = 0; k0 < K; k0 += 32) {
        short8v afrag;
        if (A_FP32) {
            const float* ap = (const float*)xa + (size_t)arow * K + k0 + koff;
            float4 a0 = *reinterpret_cast<const float4*>(ap);
            float4 a1 = *reinterpret_cast<const float4*>(ap + 4);
            afrag[0] = (short)f2bf(a0.x); afrag[1] = (short)f2bf(a0.y);
            afrag[2] = (short)f2bf(a0.z); afrag[3] = (short)f2bf(a0.w);
            afrag[4] = (short)f2bf(a1.x); afrag[5] = (short)f2bf(a1.y);
            afrag[6] = (short)f2bf(a1.z); afrag[7] = (short)f2bf(a1.w);
        } else {
            afrag = *reinterpret_cast<const short8v*>((const ushort_t*)xa + (size_t)arow * K + k0 + koff);
        }
#pragma unroll
        for (int f = 0; f < 8; f++) {
            const ushort_t* bh = (f < 4) ? wlh : wrh;
            const ushort_t* blo = (f < 4) ? wll : wrl;
            int row = ((f * 16 + wrow) & 63);
            size_t boff = (size_t)row * K + k0 + koff;
            short8v bfh = *reinterpret_cast<const short8v*>(bh + boff);
            short8v bfl = *reinterpret_cast<const short8v*>(blo + boff);
            acc[f] = __builtin_amdgcn_mfma_f32_16x16x32_bf16(afrag, bfh, acc[f], 0, 0, 0);
            acc[f] = __builtin_amdgcn_mfma_f32_16x16x32_bf16(afrag, bfl, acc[f], 0, 0, 0);
        }
    }

    int r0 = m0 + (lane >> 4) * 4;
#pragma unroll
    for (int f = 0; f < 8; f++) {
        int col = f * 16 + (lane & 15);
        float bias = (col < 64) ? bl[col] : br[col - 64];
        ushort_t* dstp = (col < 64) ? xl : xr;
        int c = col & 63;
#pragma unroll
        for (int j = 0; j < 4; j++) {
            int row = r0 + j;
            if (row < N_NODES) dstp[(size_t)row * 64 + c] = f2bf(acc[f][j] + bias);
        }
    }
}

// ---------------------------------------------------------------- fused: h = relu(concat@W.T+b) -> global_add_pool
__global__ void k_gemm_h_pool(const ushort_t* __restrict__ x1, const ushort_t* __restrict__ x2,
                              const ushort_t* __restrict__ x3,
                              const ushort_t* __restrict__ whi, const ushort_t* __restrict__ wlo,
                              const float* __restrict__ b, const int* __restrict__ batch,
                              float* __restrict__ g) {
    __shared__ float ht[64][65];
    int tid = threadIdx.x;
    int wv = tid >> 6, lane = tid & 63;
    int m0 = blockIdx.x * 64 + wv * 16;
    bool wactive = m0 < N_NODES;

    if (wactive) {
        int arow = min(m0 + (lane & 15), N_NODES - 1);
        int koff = (lane >> 4) * 8;
        int wrow = lane & 15;
        float4v acc[4];
#pragma unroll
        for (int f = 0; f < 4; f++) acc[f] = (float4v)(0.f);
#pragma unroll
        for (int ks = 0; ks < 6; ks++) {
            int k0 = ks * 32;
            const ushort_t* srcp = (ks < 2) ? x1 : (ks < 4 ? x2 : x3);
            int kc = k0 & 63;
            short8v afrag = *reinterpret_cast<const short8v*>(srcp + (size_t)arow * 64 + kc + koff);
#pragma unroll
            for (int f = 0; f < 4; f++) {
                size_t boff = (size_t)(f * 16 + wrow) * 192 + k0 + koff;
                short8v bfh = *reinterpret_cast<const short8v*>(whi + boff);
                short8v bfl = *reinterpret_cast<const short8v*>(wlo + boff);
                acc[f] = __builtin_amdgcn_mfma_f32_16x16x32_bf16(afrag, bfh, acc[f], 0, 0, 0);
                acc[f] = __builtin_amdgcn_mfma_f32_16x16x32_bf16(afrag, bfl, acc[f], 0, 0, 0);
            }
        }
        int r0 = wv * 16 + (lane >> 4) * 4;   // row within block tile
#pragma unroll
        for (int f = 0; f < 4; f++) {
            int col = f * 16 + (lane & 15);
            float bias = b[col];
#pragma unroll
            for (int j = 0; j < 4; j++) {
                float o = acc[f][j] + bias;
                ht[r0 + j][col] = o > 0.f ? o : 0.f;
            }
        }
    }
    __syncthreads();

    // pool 64 rows of ht into g by (sorted) batch index; run-detection per thread
    int c = tid & 63, rr = tid >> 6;
    int blkbase = blockIdx.x * 64;
    float acc = 0.f;
    int cur = -1;
    for (int r = rr; r < 64; r += 4) {
        int node = blkbase + r;
        if (node >= N_NODES) break;
        int bb = batch[node];
        if (bb != cur) {
            if (cur >= 0) atomicAdd(&g[cur * 64 + c], acc);
            cur = bb;
            acc = 0.f;
        }
        acc += ht[r][c];
    }
    if (cur >= 0) atomicAdd(&g[cur * 64 + c], acc);
}

// ---------------------------------------------------------------- GATv2 aggregate
// 4 nodes/wave (16 lanes, 4ch/lane), degree-ordered via order[]; log2-domain online softmax
__global__ void k_gat(const ushort_t* __restrict__ xl, const ushort_t* __restrict__ xr,
                      const int* __restrict__ rowptr, const int* __restrict__ csr_src,
                      const int* __restrict__ order,
                      const float* __restrict__ att, const float* __restrict__ bo,
                      ushort_t* __restrict__ xout) {
    int tid = threadIdx.x;
    int wv = tid >> 6, lane = tid & 63;
    int gl = lane & 15;
    int slot = blockIdx.x * 16 + wv * 4 + (lane >> 4);
    if (slot >= N_NODES) return;
    int node = order[slot];
    const float LOG2E = 1.44269504f;
    int c0 = gl * 4;
    float4 a4 = *reinterpret_cast<const float4*>(att + c0);
    float at0 = a4.x * LOG2E, at1 = a4.y * LOG2E, at2 = a4.z * LOG2E, at3 = a4.w * LOG2E;
    size_t nb = (size_t)node * 64 + c0;
    ushort4 qr = *reinterpret_cast<const ushort4*>(xr + nb);
    ushort4 ql = *reinterpret_cast<const ushort4*>(xl + nb);
    float xr0 = bf2f(qr.x), xr1 = bf2f(qr.y), xr2 = bf2f(qr.z), xr3 = bf2f(qr.w);
    float l0 = bf2f(ql.x), l1 = bf2f(ql.y), l2 = bf2f(ql.z), l3 = bf2f(ql.w);

    auto grd = [](float p) {   // sum over the 16-lane group (also broadcasts)
        p += __shfl_xor(p, 1);
        p += __shfl_xor(p, 2);
        p += __shfl_xor(p, 4);
        p += __shfl_xor(p, 8);
        return p;
    };
    auto score4 = [&](float v0, float v1, float v2, float v3) {
        float s0 = v0 + xr0, s1 = v1 + xr1, s2 = v2 + xr2, s3 = v3 + xr3;
        float t0 = fmaxf(s0, LRELU_SLOPE * s0);
        float t1 = fmaxf(s1, LRELU_SLOPE * s1);
        float t2 = fmaxf(s2, LRELU_SLOPE * s2);
        float t3 = fmaxf(s3, LRELU_SLOPE * s3);
        return ((t0 * at0 + t1 * at1) + (t2 * at2 + t3 * at3));
    };

    int beg = rowptr[node], end = rowptr[node + 1];
    int deg = end - beg;

    float m = grd(score4(l0, l1, l2, l3));   // self-loop
    float ssum = 1.f;
    float a0 = l0, a1 = l1, a2 = l2, a3 = l3;

    for (int j = 0; j < deg; j += 4) {
        int base = beg + j, lim = end - 1;
        int i1 = min(base + 1, lim), i2 = min(base + 2, lim), i3 = min(base + 3, lim);
        int s0 = csr_src[base], s1 = csr_src[i1], s2 = csr_src[i2], s3 = csr_src[i3];
        ushort4 q0 = *reinterpret_cast<const ushort4*>(xl + (size_t)s0 * 64 + c0);
        ushort4 q1 = *reinterpret_cast<const ushort4*>(xl + (size_t)s1 * 64 + c0);
        ushort4 q2 = *reinterpret_cast<const ushort4*>(xl + (size_t)s2 * 64 + c0);
        ushort4 q3 = *reinterpret_cast<const ushort4*>(xl + (size_t)s3 * 64 + c0);
        float v00 = bf2f(q0.x), v01 = bf2f(q0.y), v02 = bf2f(q0.z), v03 = bf2f(q0.w);
        float v10 = bf2f(q1.x), v11 = bf2f(q1.y), v12 = bf2f(q1.z), v13 = bf2f(q1.w);
        float v20 = bf2f(q2.x), v21 = bf2f(q2.y), v22 = bf2f(q2.z), v23 = bf2f(q2.w);
        float v30 = bf2f(q3.x), v31 = bf2f(q3.y), v32 = bf2f(q3.z), v33 = bf2f(q3.w);
        float e0 = grd(score4(v00, v01, v02, v03));
        float e1 = grd(score4(v10, v11, v12, v13));
        float e2 = grd(score4(v20, v21, v22, v23));
        float e3 = grd(score4(v30, v31, v32, v33));
        int rem = deg - j;
        if (rem < 4) {
            e3 = -1e30f;
            if (rem < 3) e2 = -1e30f;
            if (rem < 2) e1 = -1e30f;
        }
        float mn = fmaxf(fmaxf(fmaxf(e0, e1), fmaxf(e2, e3)), m);
        float sc = fast_exp2(m - mn);
        float w0 = fast_exp2(e0 - mn), w1 = fast_exp2(e1 - mn);
        float w2 = fast_exp2(e2 - mn), w3 = fast_exp2(e3 - mn);
        ssum = ssum * sc + ((w0 + w1) + (w2 + w3));
        a0 = a0 * sc + ((w0 * v00 + w1 * v10) + (w2 * v20 + w3 * v30));
        a1 = a1 * sc + ((w0 * v01 + w1 * v11) + (w2 * v21 + w3 * v31));
        a2 = a2 * sc + ((w0 * v02 + w1 * v12) + (w2 * v22 + w3 * v32));
        a3 = a3 * sc + ((w0 * v03 + w1 * v13) + (w2 * v23 + w3 * v33));
        m = mn;
    }

    float rs = 1.f / (ssum + 1e-16f);
    float4 b4 = *reinterpret_cast<const float4*>(bo + c0);
    float o0 = fmaxf(a0 * rs + b4.x, 0.f);
    float o1 = fmaxf(a1 * rs + b4.y, 0.f);
    float o2 = fmaxf(a2 * rs + b4.z, 0.f);
    float o3 = fmaxf(a3 * rs + b4.w, 0.f);
    ushort4 oq;
    oq.x = f2bf(o0); oq.y = f2bf(o1); oq.z = f2bf(o2); oq.w = f2bf(o3);
    *reinterpret_cast<ushort4*>(xout + nb) = oq;
}

// ---------------------------------------------------------------- head
__global__ void k_head(const float* __restrict__ g, const float* __restrict__ pw,
                       const float* __restrict__ pb, const float* __restrict__ cw,
                       const float* __restrict__ cb, float* __restrict__ out) {
    int gb = blockIdx.x;
    int c = threadIdx.x;
    const float* gr = g + gb * 64;
    float a = pb[c];
    const float* pwr = pw + c * 64;
#pragma unroll
    for (int k = 0; k < 64; k++) a += gr[k] * pwr[k];
    a = a > 0.f ? a : 0.f;
    float o0 = wave_sum(a * cw[c]);
    float o1 = wave_sum(a * cw[64 + c]);
    if (c == 0) {
        out[gb * 2 + 0] = o0 + cb[0];
        out[gb * 2 + 1] = o1 + cb[1];
    }
}

// ---------------------------------------------------------------- launcher
extern "C" void kernel_launch(void* const* d_in, const int* in_sizes, int n_in,
                              void* d_out, int out_size, void* d_ws, size_t ws_size,
                              hipStream_t stream) {
    const float* x    = (const float*)d_in[0];
    const int*   ei   = (const int*)d_in[1];
    const int*   bidx = (const int*)d_in[2];
    const float* wl1 = (const float*)d_in[3],  *bl1 = (const float*)d_in[4];
    const float* wr1 = (const float*)d_in[5],  *br1 = (const float*)d_in[6];
    const float* att1 = (const float*)d_in[7], *bo1 = (const float*)d_in[8];
    const float* wl2 = (const float*)d_in[9],  *bl2 = (const float*)d_in[10];
    const float* wr2 = (const float*)d_in[11], *br2 = (const float*)d_in[12];
    const float* att2 = (const float*)d_in[13], *bo2 = (const float*)d_in[14];
    const float* wl3 = (const float*)d_in[15], *bl3 = (const float*)d_in[16];
    const float* wr3 = (const float*)d_in[17], *br3 = (const float*)d_in[18];
    const float* att3 = (const float*)d_in[19], *bo3 = (const float*)d_in[20];
    const float* lw = (const float*)d_in[21], *lb = (const float*)d_in[22];
    const float* pw = (const float*)d_in[23], *pb = (const float*)d_in[24];
    const float* cw = (const float*)d_in[25], *cb = (const float*)d_in[26];
    float* out = (float*)d_out;

    char* wsb = (char*)d_ws;
    size_t off = 0;
    auto alloc = [&](size_t bytes) {
        void* p = wsb + off;
        off = (off + bytes + 255) & ~(size_t)255;
        return p;
    };
    int* cnt      = (int*)alloc((size_t)N_NODES * 4);
    int* rowptr   = (int*)alloc((size_t)(N_NODES + 1) * 4);
    int* cursor   = (int*)alloc((size_t)N_NODES * 4);
    int* blocksum = (int*)alloc((size_t)SCAN_NB * 4);
    int* bcnt     = (int*)alloc((size_t)(NBUCK + NDBIN) * 4);  // bcnt + dhist, one memset
    int* dhist    = bcnt + NBUCK;
    int* dcur     = (int*)alloc((size_t)NDBIN * 4);
    int* order    = (int*)alloc((size_t)N_NODES * 4);
    int2* stage   = (int2*)alloc((size_t)NBUCK * BCAP * 8);
    int* csr_src  = (int*)alloc((size_t)N_EDGES * 4);
    const int woff[8] = {0, 8192, 16384, 20480, 24576, 28672, 32768, 45056};
    ushort_t* whi = (ushort_t*)alloc((size_t)45056 * 2);
    ushort_t* wlo = (ushort_t*)alloc((size_t)45056 * 2);
    ushort_t* xl   = (ushort_t*)alloc((size_t)N_NODES * 64 * 2);
    ushort_t* xrr  = (ushort_t*)alloc((size_t)N_NODES * 64 * 2);
    ushort_t* x1b  = (ushort_t*)alloc((size_t)N_NODES * 64 * 2);
    ushort_t* x2b  = (ushort_t*)alloc((size_t)N_NODES * 64 * 2);
    ushort_t* x3b  = (ushort_t*)alloc((size_t)N_NODES * 64 * 2);
    float* g      = (float*)alloc((size_t)NGRAPH * 64 * 4);
    (void)ws_size; (void)in_sizes; (void)n_in; (void)out_size;

    const int* srcp = ei;
    const int* dstp = ei + N_EDGES;

    hipMemsetAsync(bcnt, 0, (size_t)(NBUCK + NDBIN) * 4, stream);
    hipMemsetAsync(g, 0, (size_t)NGRAPH * 64 * 4, stream);

    k_bucket<<<ABLK, 256, 0, stream>>>(srcp, dstp, bcnt, stage);
    k_hist2<<<NBUCK, 256, 0, stream>>>(bcnt, stage, cnt, dhist);
    k_scan1<<<SCAN_NB, 1024, 0, stream>>>(cnt, rowptr, blocksum);
    k_scan2<<<1, 128, 0, stream>>>(blocksum, dhist, dcur);
    k_scan3<<<SCAN_NB, 1024, 0, stream>>>(rowptr, blocksum, cursor);
    k_scatter2<<<NBUCK, 256, 0, stream>>>(bcnt, stage, cursor, csr_src);
    k_dscatter<<<NBUCK, 256, 0, stream>>>(cnt, dcur, order);

    WSrc ws;
    ws.s[0] = wl1; ws.s[1] = wr1; ws.s[2] = wl2; ws.s[3] = wr2;
    ws.s[4] = wl3; ws.s[5] = wr3; ws.s[6] = lw;
    for (int i = 0; i < 8; i++) ws.off[i] = woff[i];
    k_cvt_w<<<64, 256, 0, stream>>>(ws, whi, wlo);

    int gemmBlocks = (N_NODES + 63) / 64;
    int gatBlocks = (N_NODES + 15) / 16;   // 16 nodes per 256-thread block

    // layer 1
    k_gemm_dual_mfma<128, true><<<gemmBlocks, 256, 0, stream>>>(
        x, whi + woff[0], wlo + woff[0], whi + woff[1], wlo + woff[1], bl1, br1, xl, xrr);
    k_gat<<<gatBlocks, 256, 0, stream>>>(xl, xrr, rowptr, csr_src, order, att1, bo1, x1b);
    // layer 2
    k_gemm_dual_mfma<64, false><<<gemmBlocks, 256, 0, stream>>>(
        x1b, whi + woff[2], wlo + woff[2], whi + woff[3], wlo + woff[3], bl2, br2, xl, xrr);
    k_gat<<<gatBlocks, 256, 0, stream>>>(xl, xrr, rowptr, csr_src, order, att2, bo2, x2b);
    // layer 3
    k_gemm_dual_mfma<64, false><<<gemmBlocks, 256, 0, stream>>>(
        x2b, whi + woff[4], wlo + woff[4], whi + woff[5], wlo + woff[5], bl3, br3, xl, xrr);
    k_gat<<<gatBlocks, 256, 0, stream>>>(xl, xrr, rowptr, csr_src, order, att3, bo3, x3b);

    // fused head GEMM + pool, then classifier
    k_gemm_h_pool<<<gemmBlocks, 256, 0, stream>>>(x1b, x2b, x3b, whi + woff[6], wlo + woff[6],
                                                  lb, bidx, g);
    k_head<<<NGRAPH, 64, 0, stream>>>(g, pw, pb, cw, cb, out);
}

// Round 10
// 258.216 us; speedup vs baseline: 1.7499x; 1.0181x over previous
//
#include <hip/hip_runtime.h>
#include <hip/hip_bf16.h>

#define N_NODES 50000
#define N_EDGES 800000
#define FDIM 128
#define CDIM 64
#define NGRAPH 256
#define LRELU_SLOPE 0.2f
#define NBUCK ((N_NODES + 255) / 256)       // 196 buckets of 256 nodes
#define BCAP 5120                            // stage capacity/bucket
#define ABLK 400                             // pass-A blocks
#define EPB ((N_EDGES + ABLK - 1) / ABLK)    // 2000 edges per pass-A block
#define NDBIN 64                             // degree bins for node ordering

typedef unsigned short ushort_t;
typedef unsigned int uint_t;
typedef __attribute__((ext_vector_type(8))) short short8v;
typedef __attribute__((ext_vector_type(4))) float float4v;

// ---------------------------------------------------------------- bf16 helpers (RNE)
__device__ __forceinline__ ushort_t f2bf(float f) {
    uint_t u = __float_as_uint(f);
    u += 0x7FFFu + ((u >> 16) & 1u);
    return (ushort_t)(u >> 16);
}
__device__ __forceinline__ float bf2f(ushort_t u) {
    return __uint_as_float(((uint_t)u) << 16);
}

__device__ __forceinline__ float fast_exp2(float x) {
    return __builtin_amdgcn_exp2f(x);
}

__device__ __forceinline__ int wave_incl_scan(int v, int lane) {
#pragma unroll
    for (int off = 1; off < 64; off <<= 1) {
        int t = __shfl_up(v, off);
        if (lane >= off) v += t;
    }
    return v;
}

__device__ __forceinline__ float wave_sum(float v) {
#pragma unroll
    for (int off = 32; off >= 1; off >>= 1) v += __shfl_xor(v, off);
    return v;
}

// ---------------------------------------------------------------- CSR build
// pass A: bucket edges by dst>>8
__global__ void k_bucket(const int* __restrict__ src, const int* __restrict__ dst,
                         int* __restrict__ bcnt, int2* __restrict__ stage) {
    __shared__ int lhist[NBUCK];
    __shared__ int lbase[NBUCK];
    __shared__ int lcur[NBUCK];
    int tid = threadIdx.x;
    int e0 = blockIdx.x * EPB;
    int e1 = min(e0 + EPB, N_EDGES);
    for (int t = tid; t < NBUCK; t += 256) { lhist[t] = 0; lcur[t] = 0; }
    __syncthreads();
    for (int e = e0 + tid; e < e1; e += 256)
        atomicAdd(&lhist[dst[e] >> 8], 1);
    __syncthreads();
    for (int t = tid; t < NBUCK; t += 256)
        lbase[t] = atomicAdd(&bcnt[t], lhist[t]);
    __syncthreads();
    for (int e = e0 + tid; e < e1; e += 256) {
        int s = src[e], d = dst[e];
        int b = d >> 8;
        int loff = atomicAdd(&lcur[b], 1);
        int pos = lbase[b] + loff;
        if (pos < BCAP) stage[(size_t)b * BCAP + pos] = make_int2(s, d);
    }
}

// exclusive scan of the 196 bucket counts (one block)
__global__ void k_bscan(const int* __restrict__ bcnt, int* __restrict__ bbase) {
    __shared__ int wsum[4];
    int tid = threadIdx.x;
    int lane = tid & 63, w = tid >> 6;
    int v = (tid < NBUCK) ? bcnt[tid] : 0;
    int incl = wave_incl_scan(v, lane);
    if (lane == 63) wsum[w] = incl;
    __syncthreads();
    if (tid == 0) {
        int s = 0;
#pragma unroll
        for (int k = 0; k < 4; k++) { int t = wsum[k]; wsum[k] = s; s += t; }
    }
    __syncthreads();
    if (tid < NBUCK) bbase[tid] = incl - v + wsum[w];
}

// fused per-bucket: node hist + local scan -> rowptr/cnt/dhist + LDS-cursor scatter
__global__ void k_csr(const int* __restrict__ bcnt, const int* __restrict__ bbase,
                      const int2* __restrict__ stage, int* __restrict__ rowptr,
                      int* __restrict__ cnt, int* __restrict__ dhist,
                      int* __restrict__ csr_src) {
    __shared__ int lcnt[256];
    __shared__ int lcur[256];
    __shared__ int ldh[NDBIN];
    __shared__ int wsum[4];
    int b = blockIdx.x;
    int tid = threadIdx.x;
    int lane = tid & 63, w = tid >> 6;
    lcnt[tid] = 0;
    if (tid < NDBIN) ldh[tid] = 0;
    __syncthreads();
    int n = min(bcnt[b], BCAP);
    const int2* sp = stage + (size_t)b * BCAP;
    for (int i = tid; i < n; i += 256)
        atomicAdd(&lcnt[sp[i].y & 255], 1);
    __syncthreads();
    int v = lcnt[tid];
    int incl = wave_incl_scan(v, lane);
    if (lane == 63) wsum[w] = incl;
    __syncthreads();
    if (tid == 0) {
        int s = 0;
#pragma unroll
        for (int k = 0; k < 4; k++) { int t = wsum[k]; wsum[k] = s; s += t; }
    }
    __syncthreads();
    int excl = incl - v + wsum[w];
    int bb = bbase[b];
    int node = (b << 8) + tid;
    if (node < N_NODES) {
        rowptr[node] = bb + excl;
        cnt[node] = v;
        atomicAdd(&ldh[min(v, NDBIN - 1)], 1);
    }
    lcur[tid] = excl;
    __syncthreads();
    if (tid < NDBIN && ldh[tid]) atomicAdd(&dhist[tid], ldh[tid]);
    if (b == 0 && tid == 0) rowptr[N_NODES] = N_EDGES;
    for (int i = tid; i < n; i += 256) {
        int2 sd = sp[i];
        int pos = atomicAdd(&lcur[sd.y & 255], 1);
        csr_src[bb + pos] = sd.x;
    }
}

// scan degree hist -> dcur (one wave)
__global__ void k_scan2d(const int* __restrict__ dhist, int* __restrict__ dcur) {
    int lane = threadIdx.x;
    int v = dhist[lane];
    int incl = wave_incl_scan(v, lane);
    dcur[lane] = incl - v;
}

// degree-binned node ordering
__global__ void k_dscatter(const int* __restrict__ cnt, int* __restrict__ dcur,
                           int* __restrict__ order) {
    __shared__ int lh[NDBIN], lb[NDBIN], lc[NDBIN];
    int b = blockIdx.x, tid = threadIdx.x;
    if (tid < NDBIN) { lh[tid] = 0; lc[tid] = 0; }
    __syncthreads();
    int node = b * 256 + tid;
    bool ok = node < N_NODES;
    int dg = ok ? min(cnt[node], NDBIN - 1) : 0;
    if (ok) atomicAdd(&lh[dg], 1);
    __syncthreads();
    if (tid < NDBIN) lb[tid] = lh[tid] ? atomicAdd(&dcur[tid], lh[tid]) : 0;
    __syncthreads();
    if (ok) {
        int off2 = atomicAdd(&lc[dg], 1);
        order[lb[dg] + off2] = node;
    }
}

// ---------------------------------------------------------------- weight f32 -> hi/lo bf16
struct WSrc {
    const float* s[7];
    int off[8];
};
__global__ void k_cvt_w(WSrc ws, ushort_t* __restrict__ hi, ushort_t* __restrict__ lo) {
    int gid = blockIdx.x * 256 + threadIdx.x;
    int stride = gridDim.x * 256;
#pragma unroll
    for (int mi = 0; mi < 7; mi++) {
        int n = ws.off[mi + 1] - ws.off[mi];
        const float* s = ws.s[mi];
        ushort_t* h = hi + ws.off[mi];
        ushort_t* l = lo + ws.off[mi];
        for (int i = gid; i < n; i += stride) {
            float f = s[i];
            ushort_t hb = f2bf(f);
            h[i] = hb;
            l[i] = f2bf(f - bf2f(hb));
        }
    }
}

// ---------------------------------------------------------------- dual projection via MFMA
template <int K, bool A_FP32>
__global__ void k_gemm_dual_mfma(const void* __restrict__ xa,
                                 const ushort_t* __restrict__ wlh, const ushort_t* __restrict__ wll,
                                 const ushort_t* __restrict__ wrh, const ushort_t* __restrict__ wrl,
                                 const float* __restrict__ bl, const float* __restrict__ br,
                                 ushort_t* __restrict__ xl, ushort_t* __restrict__ xr) {
    int tid = threadIdx.x;
    int wv = tid >> 6, lane = tid & 63;
    int m0 = blockIdx.x * 64 + wv * 16;
    if (m0 >= N_NODES) return;
    int arow = min(m0 + (lane & 15), N_NODES - 1);
    int koff = (lane >> 4) * 8;
    int wrow = lane & 15;

    float4v acc[8];
#pragma unroll
    for (int f = 0; f < 8; f++) acc[f] = (float4v)(0.f);

#pragma unroll
    for (int k0 = 0; k0 < K; k0 += 32) {
        short8v afrag;
        if (A_FP32) {
            const float* ap = (const float*)xa + (size_t)arow * K + k0 + koff;
            float4 a0 = *reinterpret_cast<const float4*>(ap);
            float4 a1 = *reinterpret_cast<const float4*>(ap + 4);
            afrag[0] = (short)f2bf(a0.x); afrag[1] = (short)f2bf(a0.y);
            afrag[2] = (short)f2bf(a0.z); afrag[3] = (short)f2bf(a0.w);
            afrag[4] = (short)f2bf(a1.x); afrag[5] = (short)f2bf(a1.y);
            afrag[6] = (short)f2bf(a1.z); afrag[7] = (short)f2bf(a1.w);
        } else {
            afrag = *reinterpret_cast<const short8v*>((const ushort_t*)xa + (size_t)arow * K + k0 + koff);
        }
#pragma unroll
        for (int f = 0; f < 8; f++) {
            const ushort_t* bh = (f < 4) ? wlh : wrh;
            const ushort_t* blo = (f < 4) ? wll : wrl;
            int row = ((f * 16 + wrow) & 63);
            size_t boff = (size_t)row * K + k0 + koff;
            short8v bfh = *reinterpret_cast<const short8v*>(bh + boff);
            short8v bfl = *reinterpret_cast<const short8v*>(blo + boff);
            acc[f] = __builtin_amdgcn_mfma_f32_16x16x32_bf16(afrag, bfh, acc[f], 0, 0, 0);
            acc[f] = __builtin_amdgcn_mfma_f32_16x16x32_bf16(afrag, bfl, acc[f], 0, 0, 0);
        }
    }

    int r0 = m0 + (lane >> 4) * 4;
#pragma unroll
    for (int f = 0; f < 8; f++) {
        int col = f * 16 + (lane & 15);
        float bias = (col < 64) ? bl[col] : br[col - 64];
        ushort_t* dstp = (col < 64) ? xl : xr;
        int c = col & 63;
#pragma unroll
        for (int j = 0; j < 4; j++) {
            int row = r0 + j;
            if (row < N_NODES) dstp[(size_t)row * 64 + c] = f2bf(acc[f][j] + bias);
        }
    }
}

// ---------------------------------------------------------------- fused: h = relu(concat@W.T+b) -> global_add_pool
__global__ void k_gemm_h_pool(const ushort_t* __restrict__ x1, const ushort_t* __restrict__ x2,
                              const ushort_t* __restrict__ x3,
                              const ushort_t* __restrict__ whi, const ushort_t* __restrict__ wlo,
                              const float* __restrict__ b, const int* __restrict__ batch,
                              float* __restrict__ g) {
    __shared__ float ht[64][65];
    int tid = threadIdx.x;
    int wv = tid >> 6, lane = tid & 63;
    int m0 = blockIdx.x * 64 + wv * 16;
    bool wactive = m0 < N_NODES;

    if (wactive) {
        int arow = min(m0 + (lane & 15), N_NODES - 1);
        int koff = (lane >> 4) * 8;
        int wrow = lane & 15;
        float4v acc[4];
#pragma unroll
        for (int f = 0; f < 4; f++) acc[f] = (float4v)(0.f);
#pragma unroll
        for (int ks = 0; ks < 6; ks++) {
            int k0 = ks * 32;
            const ushort_t* srcp = (ks < 2) ? x1 : (ks < 4 ? x2 : x3);
            int kc = k0 & 63;
            short8v afrag = *reinterpret_cast<const short8v*>(srcp + (size_t)arow * 64 + kc + koff);
#pragma unroll
            for (int f = 0; f < 4; f++) {
                size_t boff = (size_t)(f * 16 + wrow) * 192 + k0 + koff;
                short8v bfh = *reinterpret_cast<const short8v*>(whi + boff);
                short8v bfl = *reinterpret_cast<const short8v*>(wlo + boff);
                acc[f] = __builtin_amdgcn_mfma_f32_16x16x32_bf16(afrag, bfh, acc[f], 0, 0, 0);
                acc[f] = __builtin_amdgcn_mfma_f32_16x16x32_bf16(afrag, bfl, acc[f], 0, 0, 0);
            }
        }
        int r0 = wv * 16 + (lane >> 4) * 4;
#pragma unroll
        for (int f = 0; f < 4; f++) {
            int col = f * 16 + (lane & 15);
            float bias = b[col];
#pragma unroll
            for (int j = 0; j < 4; j++) {
                float o = acc[f][j] + bias;
                ht[r0 + j][col] = o > 0.f ? o : 0.f;
            }
        }
    }
    __syncthreads();

    int c = tid & 63, rr = tid >> 6;
    int blkbase = blockIdx.x * 64;
    float acc = 0.f;
    int cur = -1;
    for (int r = rr; r < 64; r += 4) {
        int node = blkbase + r;
        if (node >= N_NODES) break;
        int bb = batch[node];
        if (bb != cur) {
            if (cur >= 0) atomicAdd(&g[cur * 64 + c], acc);
            cur = bb;
            acc = 0.f;
        }
        acc += ht[r][c];
    }
    if (cur >= 0) atomicAdd(&g[cur * 64 + c], acc);
}

// ---------------------------------------------------------------- GATv2 aggregate
// 4 nodes/wave (16 lanes, 4ch/lane), degree-ordered; 8-edge unrolled online softmax (log2 domain)
__global__ void k_gat(const ushort_t* __restrict__ xl, const ushort_t* __restrict__ xr,
                      const int* __restrict__ rowptr, const int* __restrict__ csr_src,
                      const int* __restrict__ order,
                      const float* __restrict__ att, const float* __restrict__ bo,
                      ushort_t* __restrict__ xout) {
    int tid = threadIdx.x;
    int wv = tid >> 6, lane = tid & 63;
    int gl = lane & 15;
    int slot = blockIdx.x * 16 + wv * 4 + (lane >> 4);
    if (slot >= N_NODES) return;
    int node = order[slot];
    const float LOG2E = 1.44269504f;
    int c0 = gl * 4;
    float4 a4 = *reinterpret_cast<const float4*>(att + c0);
    float at0 = a4.x * LOG2E, at1 = a4.y * LOG2E, at2 = a4.z * LOG2E, at3 = a4.w * LOG2E;
    size_t nb = (size_t)node * 64 + c0;
    ushort4 qr = *reinterpret_cast<const ushort4*>(xr + nb);
    ushort4 ql = *reinterpret_cast<const ushort4*>(xl + nb);
    float xr0 = bf2f(qr.x), xr1 = bf2f(qr.y), xr2 = bf2f(qr.z), xr3 = bf2f(qr.w);
    float l0 = bf2f(ql.x), l1 = bf2f(ql.y), l2 = bf2f(ql.z), l3 = bf2f(ql.w);

    auto grd = [](float p) {   // sum over the 16-lane group (also broadcasts)
        p += __shfl_xor(p, 1);
        p += __shfl_xor(p, 2);
        p += __shfl_xor(p, 4);
        p += __shfl_xor(p, 8);
        return p;
    };
    auto score4 = [&](float v0, float v1, float v2, float v3) {
        float s0 = v0 + xr0, s1 = v1 + xr1, s2 = v2 + xr2, s3 = v3 + xr3;
        float t0 = fmaxf(s0, LRELU_SLOPE * s0);
        float t1 = fmaxf(s1, LRELU_SLOPE * s1);
        float t2 = fmaxf(s2, LRELU_SLOPE * s2);
        float t3 = fmaxf(s3, LRELU_SLOPE * s3);
        return ((t0 * at0 + t1 * at1) + (t2 * at2 + t3 * at3));
    };

    int beg = rowptr[node], end = rowptr[node + 1];
    int deg = end - beg;
    int lim = end - 1;

    float m = grd(score4(l0, l1, l2, l3));   // self-loop
    float ssum = 1.f;
    float a0 = l0, a1 = l1, a2 = l2, a3 = l3;

    for (int j = 0; j < deg; j += 8) {
        int base = beg + j;
        int i0 = base;
        int i1 = min(base + 1, lim), i2 = min(base + 2, lim), i3 = min(base + 3, lim);
        int i4 = min(base + 4, lim), i5 = min(base + 5, lim);
        int i6 = min(base + 6, lim), i7 = min(base + 7, lim);
        int s0 = csr_src[i0], s1 = csr_src[i1], s2 = csr_src[i2], s3 = csr_src[i3];
        int s4 = csr_src[i4], s5 = csr_src[i5], s6 = csr_src[i6], s7 = csr_src[i7];
        ushort4 q0 = *reinterpret_cast<const ushort4*>(xl + (size_t)s0 * 64 + c0);
        ushort4 q1 = *reinterpret_cast<const ushort4*>(xl + (size_t)s1 * 64 + c0);
        ushort4 q2 = *reinterpret_cast<const ushort4*>(xl + (size_t)s2 * 64 + c0);
        ushort4 q3 = *reinterpret_cast<const ushort4*>(xl + (size_t)s3 * 64 + c0);
        ushort4 q4 = *reinterpret_cast<const ushort4*>(xl + (size_t)s4 * 64 + c0);
        ushort4 q5 = *reinterpret_cast<const ushort4*>(xl + (size_t)s5 * 64 + c0);
        ushort4 q6 = *reinterpret_cast<const ushort4*>(xl + (size_t)s6 * 64 + c0);
        ushort4 q7 = *reinterpret_cast<const ushort4*>(xl + (size_t)s7 * 64 + c0);
        float v00 = bf2f(q0.x), v01 = bf2f(q0.y), v02 = bf2f(q0.z), v03 = bf2f(q0.w);
        float v10 = bf2f(q1.x), v11 = bf2f(q1.y), v12 = bf2f(q1.z), v13 = bf2f(q1.w);
        float v20 = bf2f(q2.x), v21 = bf2f(q2.y), v22 = bf2f(q2.z), v23 = bf2f(q2.w);
        float v30 = bf2f(q3.x), v31 = bf2f(q3.y), v32 = bf2f(q3.z), v33 = bf2f(q3.w);
        float v40 = bf2f(q4.x), v41 = bf2f(q4.y), v42 = bf2f(q4.z), v43 = bf2f(q4.w);
        float v50 = bf2f(q5.x), v51 = bf2f(q5.y), v52 = bf2f(q5.z), v53 = bf2f(q5.w);
        float v60 = bf2f(q6.x), v61 = bf2f(q6.y), v62 = bf2f(q6.z), v63 = bf2f(q6.w);
        float v70 = bf2f(q7.x), v71 = bf2f(q7.y), v72 = bf2f(q7.z), v73 = bf2f(q7.w);
        float e0 = grd(score4(v00, v01, v02, v03));
        float e1 = grd(score4(v10, v11, v12, v13));
        float e2 = grd(score4(v20, v21, v22, v23));
        float e3 = grd(score4(v30, v31, v32, v33));
        float e4 = grd(score4(v40, v41, v42, v43));
        float e5 = grd(score4(v50, v51, v52, v53));
        float e6 = grd(score4(v60, v61, v62, v63));
        float e7 = grd(score4(v70, v71, v72, v73));
        int rem = deg - j;
        if (rem < 8) {
            e1 = (rem > 1) ? e1 : -1e30f;
            e2 = (rem > 2) ? e2 : -1e30f;
            e3 = (rem > 3) ? e3 : -1e30f;
            e4 = (rem > 4) ? e4 : -1e30f;
            e5 = (rem > 5) ? e5 : -1e30f;
            e6 = (rem > 6) ? e6 : -1e30f;
            e7 = (rem > 7) ? e7 : -1e30f;
        }
        float mx = fmaxf(fmaxf(fmaxf(e0, e1), fmaxf(e2, e3)),
                         fmaxf(fmaxf(e4, e5), fmaxf(e6, e7)));
        float mn = fmaxf(m, mx);
        float sc = fast_exp2(m - mn);
        float w0 = fast_exp2(e0 - mn), w1 = fast_exp2(e1 - mn);
        float w2 = fast_exp2(e2 - mn), w3 = fast_exp2(e3 - mn);
        float w4 = fast_exp2(e4 - mn), w5 = fast_exp2(e5 - mn);
        float w6 = fast_exp2(e6 - mn), w7 = fast_exp2(e7 - mn);
        ssum = ssum * sc + (((w0 + w1) + (w2 + w3)) + ((w4 + w5) + (w6 + w7)));
        a0 = a0 * sc + (((w0 * v00 + w1 * v10) + (w2 * v20 + w3 * v30)) +
                        ((w4 * v40 + w5 * v50) + (w6 * v60 + w7 * v70)));
        a1 = a1 * sc + (((w0 * v01 + w1 * v11) + (w2 * v21 + w3 * v31)) +
                        ((w4 * v41 + w5 * v51) + (w6 * v61 + w7 * v71)));
        a2 = a2 * sc + (((w0 * v02 + w1 * v12) + (w2 * v22 + w3 * v32)) +
                        ((w4 * v42 + w5 * v52) + (w6 * v62 + w7 * v72)));
        a3 = a3 * sc + (((w0 * v03 + w1 * v13) + (w2 * v23 + w3 * v33)) +
                        ((w4 * v43 + w5 * v53) + (w6 * v63 + w7 * v73)));
        m = mn;
    }

    float rs = 1.f / (ssum + 1e-16f);
    float4 b4 = *reinterpret_cast<const float4*>(bo + c0);
    float o0 = fmaxf(a0 * rs + b4.x, 0.f);
    float o1 = fmaxf(a1 * rs + b4.y, 0.f);
    float o2 = fmaxf(a2 * rs + b4.z, 0.f);
    float o3 = fmaxf(a3 * rs + b4.w, 0.f);
    ushort4 oq;
    oq.x = f2bf(o0); oq.y = f2bf(o1); oq.z = f2bf(o2); oq.w = f2bf(o3);
    *reinterpret_cast<ushort4*>(xout + nb) = oq;
}

// ---------------------------------------------------------------- head
__global__ void k_head(const float* __restrict__ g, const float* __restrict__ pw,
                       const float* __restrict__ pb, const float* __restrict__ cw,
                       const float* __restrict__ cb, float* __restrict__ out) {
    int gb = blockIdx.x;
    int c = threadIdx.x;
    const float* gr = g + gb * 64;
    float a = pb[c];
    const float* pwr = pw + c * 64;
#pragma unroll
    for (int k = 0; k < 64; k++) a += gr[k] * pwr[k];
    a = a > 0.f ? a : 0.f;
    float o0 = wave_sum(a * cw[c]);
    float o1 = wave_sum(a * cw[64 + c]);
    if (c == 0) {
        out[gb * 2 + 0] = o0 + cb[0];
        out[gb * 2 + 1] = o1 + cb[1];
    }
}

// ---------------------------------------------------------------- launcher
extern "C" void kernel_launch(void* const* d_in, const int* in_sizes, int n_in,
                              void* d_out, int out_size, void* d_ws, size_t ws_size,
                              hipStream_t stream) {
    const float* x    = (const float*)d_in[0];
    const int*   ei   = (const int*)d_in[1];
    const int*   bidx = (const int*)d_in[2];
    const float* wl1 = (const float*)d_in[3],  *bl1 = (const float*)d_in[4];
    const float* wr1 = (const float*)d_in[5],  *br1 = (const float*)d_in[6];
    const float* att1 = (const float*)d_in[7], *bo1 = (const float*)d_in[8];
    const float* wl2 = (const float*)d_in[9],  *bl2 = (const float*)d_in[10];
    const float* wr2 = (const float*)d_in[11], *br2 = (const float*)d_in[12];
    const float* att2 = (const float*)d_in[13], *bo2 = (const float*)d_in[14];
    const float* wl3 = (const float*)d_in[15], *bl3 = (const float*)d_in[16];
    const float* wr3 = (const float*)d_in[17], *br3 = (const float*)d_in[18];
    const float* att3 = (const float*)d_in[19], *bo3 = (const float*)d_in[20];
    const float* lw = (const float*)d_in[21], *lb = (const float*)d_in[22];
    const float* pw = (const float*)d_in[23], *pb = (const float*)d_in[24];
    const float* cw = (const float*)d_in[25], *cb = (const float*)d_in[26];
    float* out = (float*)d_out;

    char* wsb = (char*)d_ws;
    size_t off = 0;
    auto alloc = [&](size_t bytes) {
        void* p = wsb + off;
        off = (off + bytes + 255) & ~(size_t)255;
        return p;
    };
    int* cnt      = (int*)alloc((size_t)N_NODES * 4);
    int* rowptr   = (int*)alloc((size_t)(N_NODES + 1) * 4);
    int* bcnt     = (int*)alloc((size_t)(NBUCK + NDBIN) * 4);  // bcnt + dhist, one memset
    int* dhist    = bcnt + NBUCK;
    int* bbase    = (int*)alloc((size_t)NBUCK * 4);
    int* dcur     = (int*)alloc((size_t)NDBIN * 4);
    int* order    = (int*)alloc((size_t)N_NODES * 4);
    int2* stage   = (int2*)alloc((size_t)NBUCK * BCAP * 8);
    int* csr_src  = (int*)alloc((size_t)N_EDGES * 4);
    const int woff[8] = {0, 8192, 16384, 20480, 24576, 28672, 32768, 45056};
    ushort_t* whi = (ushort_t*)alloc((size_t)45056 * 2);
    ushort_t* wlo = (ushort_t*)alloc((size_t)45056 * 2);
    ushort_t* xl   = (ushort_t*)alloc((size_t)N_NODES * 64 * 2);
    ushort_t* xrr  = (ushort_t*)alloc((size_t)N_NODES * 64 * 2);
    ushort_t* x1b  = (ushort_t*)alloc((size_t)N_NODES * 64 * 2);
    ushort_t* x2b  = (ushort_t*)alloc((size_t)N_NODES * 64 * 2);
    ushort_t* x3b  = (ushort_t*)alloc((size_t)N_NODES * 64 * 2);
    float* g      = (float*)alloc((size_t)NGRAPH * 64 * 4);
    (void)ws_size; (void)in_sizes; (void)n_in; (void)out_size;

    const int* srcp = ei;
    const int* dstp = ei + N_EDGES;

    hipMemsetAsync(bcnt, 0, (size_t)(NBUCK + NDBIN) * 4, stream);
    hipMemsetAsync(g, 0, (size_t)NGRAPH * 64 * 4, stream);

    k_bucket<<<ABLK, 256, 0, stream>>>(srcp, dstp, bcnt, stage);
    k_bscan<<<1, 256, 0, stream>>>(bcnt, bbase);
    k_csr<<<NBUCK, 256, 0, stream>>>(bcnt, bbase, stage, rowptr, cnt, dhist, csr_src);
    k_scan2d<<<1, 64, 0, stream>>>(dhist, dcur);
    k_dscatter<<<NBUCK, 256, 0, stream>>>(cnt, dcur, order);

    WSrc ws;
    ws.s[0] = wl1; ws.s[1] = wr1; ws.s[2] = wl2; ws.s[3] = wr2;
    ws.s[4] = wl3; ws.s[5] = wr3; ws.s[6] = lw;
    for (int i = 0; i < 8; i++) ws.off[i] = woff[i];
    k_cvt_w<<<64, 256, 0, stream>>>(ws, whi, wlo);

    int gemmBlocks = (N_NODES + 63) / 64;
    int gatBlocks = (N_NODES + 15) / 16;

    // layer 1
    k_gemm_dual_mfma<128, true><<<gemmBlocks, 256, 0, stream>>>(
        x, whi + woff[0], wlo + woff[0], whi + woff[1], wlo + woff[1], bl1, br1, xl, xrr);
    k_gat<<<gatBlocks, 256, 0, stream>>>(xl, xrr, rowptr, csr_src, order, att1, bo1, x1b);
    // layer 2
    k_gemm_dual_mfma<64, false><<<gemmBlocks, 256, 0, stream>>>(
        x1b, whi + woff[2], wlo + woff[2], whi + woff[3], wlo + woff[3], bl2, br2, xl, xrr);
    k_gat<<<gatBlocks, 256, 0, stream>>>(xl, xrr, rowptr, csr_src, order, att2, bo2, x2b);
    // layer 3
    k_gemm_dual_mfma<64, false><<<gemmBlocks, 256, 0, stream>>>(
        x2b, whi + woff[4], wlo + woff[4], whi + woff[5], wlo + woff[5], bl3, br3, xl, xrr);
    k_gat<<<gatBlocks, 256, 0, stream>>>(xl, xrr, rowptr, csr_src, order, att3, bo3, x3b);

    // fused head GEMM + pool, then classifier
    k_gemm_h_pool<<<gemmBlocks, 256, 0, stream>>>(x1b, x2b, x3b, whi + woff[6], wlo + woff[6],
                                                  lb, bidx, g);
    k_head<<<NGRAPH, 64, 0, stream>>>(g, pw, pb, cw, cb, out);
}

// Round 11
// 254.007 us; speedup vs baseline: 1.7789x; 1.0166x over previous
//
#include <hip/hip_runtime.h>
#include <hip/hip_bf16.h>

#define N_NODES 50000
#define N_EDGES 800000
#define FDIM 128
#define CDIM 64
#define NGRAPH 256
#define LRELU_SLOPE 0.2f
#define NBUCK ((N_NODES + 255) / 256)       // 196 buckets of 256 nodes
#define BCAP 5120                            // stage capacity/bucket
#define ABLK 400                             // pass-A blocks
#define EPB ((N_EDGES + ABLK - 1) / ABLK)    // 2000 edges per pass-A block
#define NDBIN 64                             // degree bins for node ordering
#define GEMMB ((N_NODES + 63) / 64)          // 782 row-tiles

typedef unsigned short ushort_t;
typedef unsigned int uint_t;
typedef __attribute__((ext_vector_type(8))) short short8v;
typedef __attribute__((ext_vector_type(4))) float float4v;

// ---------------------------------------------------------------- bf16 helpers (RNE)
__device__ __forceinline__ ushort_t f2bf(float f) {
    uint_t u = __float_as_uint(f);
    u += 0x7FFFu + ((u >> 16) & 1u);
    return (ushort_t)(u >> 16);
}
__device__ __forceinline__ float bf2f(ushort_t u) {
    return __uint_as_float(((uint_t)u) << 16);
}

__device__ __forceinline__ float fast_exp2(float x) {
    return __builtin_amdgcn_exp2f(x);
}

__device__ __forceinline__ int wave_incl_scan(int v, int lane) {
#pragma unroll
    for (int off = 1; off < 64; off <<= 1) {
        int t = __shfl_up(v, off);
        if (lane >= off) v += t;
    }
    return v;
}

__device__ __forceinline__ float wave_sum(float v) {
#pragma unroll
    for (int off = 32; off >= 1; off >>= 1) v += __shfl_xor(v, off);
    return v;
}

// ---------------------------------------------------------------- x fp32 -> bf16 (coalesced stream)
__global__ void k_cvt_x(const float* __restrict__ x, ushort_t* __restrict__ xb) {
    int i = blockIdx.x * 256 + threadIdx.x;   // octet index
    const int TOT = N_NODES * FDIM / 8;       // 800000
    if (i >= TOT) return;
    const float* p = x + (size_t)i * 8;
    float4 a = *reinterpret_cast<const float4*>(p);
    float4 b = *reinterpret_cast<const float4*>(p + 4);
    short8v o;
    o[0] = (short)f2bf(a.x); o[1] = (short)f2bf(a.y);
    o[2] = (short)f2bf(a.z); o[3] = (short)f2bf(a.w);
    o[4] = (short)f2bf(b.x); o[5] = (short)f2bf(b.y);
    o[6] = (short)f2bf(b.z); o[7] = (short)f2bf(b.w);
    *reinterpret_cast<short8v*>(xb + (size_t)i * 8) = o;
}

// ---------------------------------------------------------------- CSR build
__global__ void k_bucket(const int* __restrict__ src, const int* __restrict__ dst,
                         int* __restrict__ bcnt, int2* __restrict__ stage) {
    __shared__ int lhist[NBUCK];
    __shared__ int lbase[NBUCK];
    __shared__ int lcur[NBUCK];
    int tid = threadIdx.x;
    int e0 = blockIdx.x * EPB;
    int e1 = min(e0 + EPB, N_EDGES);
    for (int t = tid; t < NBUCK; t += 256) { lhist[t] = 0; lcur[t] = 0; }
    __syncthreads();
    for (int e = e0 + tid; e < e1; e += 256)
        atomicAdd(&lhist[dst[e] >> 8], 1);
    __syncthreads();
    for (int t = tid; t < NBUCK; t += 256)
        lbase[t] = atomicAdd(&bcnt[t], lhist[t]);
    __syncthreads();
    for (int e = e0 + tid; e < e1; e += 256) {
        int s = src[e], d = dst[e];
        int b = d >> 8;
        int loff = atomicAdd(&lcur[b], 1);
        int pos = lbase[b] + loff;
        if (pos < BCAP) stage[(size_t)b * BCAP + pos] = make_int2(s, d);
    }
}

__global__ void k_bscan(const int* __restrict__ bcnt, int* __restrict__ bbase) {
    __shared__ int wsum[4];
    int tid = threadIdx.x;
    int lane = tid & 63, w = tid >> 6;
    int v = (tid < NBUCK) ? bcnt[tid] : 0;
    int incl = wave_incl_scan(v, lane);
    if (lane == 63) wsum[w] = incl;
    __syncthreads();
    if (tid == 0) {
        int s = 0;
#pragma unroll
        for (int k = 0; k < 4; k++) { int t = wsum[k]; wsum[k] = s; s += t; }
    }
    __syncthreads();
    if (tid < NBUCK) bbase[tid] = incl - v + wsum[w];
}

__global__ void k_csr(const int* __restrict__ bcnt, const int* __restrict__ bbase,
                      const int2* __restrict__ stage, int* __restrict__ rowptr,
                      int* __restrict__ cnt, int* __restrict__ dhist,
                      int* __restrict__ csr_src) {
    __shared__ int lcnt[256];
    __shared__ int lcur[256];
    __shared__ int ldh[NDBIN];
    __shared__ int wsum[4];
    int b = blockIdx.x;
    int tid = threadIdx.x;
    int lane = tid & 63, w = tid >> 6;
    lcnt[tid] = 0;
    if (tid < NDBIN) ldh[tid] = 0;
    __syncthreads();
    int n = min(bcnt[b], BCAP);
    const int2* sp = stage + (size_t)b * BCAP;
    for (int i = tid; i < n; i += 256)
        atomicAdd(&lcnt[sp[i].y & 255], 1);
    __syncthreads();
    int v = lcnt[tid];
    int incl = wave_incl_scan(v, lane);
    if (lane == 63) wsum[w] = incl;
    __syncthreads();
    if (tid == 0) {
        int s = 0;
#pragma unroll
        for (int k = 0; k < 4; k++) { int t = wsum[k]; wsum[k] = s; s += t; }
    }
    __syncthreads();
    int excl = incl - v + wsum[w];
    int bb = bbase[b];
    int node = (b << 8) + tid;
    if (node < N_NODES) {
        rowptr[node] = bb + excl;
        cnt[node] = v;
        atomicAdd(&ldh[min(v, NDBIN - 1)], 1);
    }
    lcur[tid] = excl;
    __syncthreads();
    if (tid < NDBIN && ldh[tid]) atomicAdd(&dhist[tid], ldh[tid]);
    if (b == 0 && tid == 0) rowptr[N_NODES] = N_EDGES;
    for (int i = tid; i < n; i += 256) {
        int2 sd = sp[i];
        int pos = atomicAdd(&lcur[sd.y & 255], 1);
        csr_src[bb + pos] = sd.x;
    }
}

__global__ void k_scan2d(const int* __restrict__ dhist, int* __restrict__ dcur) {
    int lane = threadIdx.x;
    int v = dhist[lane];
    int incl = wave_incl_scan(v, lane);
    dcur[lane] = incl - v;
}

__global__ void k_dscatter(const int* __restrict__ cnt, int* __restrict__ dcur,
                           int* __restrict__ order) {
    __shared__ int lh[NDBIN], lb[NDBIN], lc[NDBIN];
    int b = blockIdx.x, tid = threadIdx.x;
    if (tid < NDBIN) { lh[tid] = 0; lc[tid] = 0; }
    __syncthreads();
    int node = b * 256 + tid;
    bool ok = node < N_NODES;
    int dg = ok ? min(cnt[node], NDBIN - 1) : 0;
    if (ok) atomicAdd(&lh[dg], 1);
    __syncthreads();
    if (tid < NDBIN) lb[tid] = lh[tid] ? atomicAdd(&dcur[tid], lh[tid]) : 0;
    __syncthreads();
    if (ok) {
        int off2 = atomicAdd(&lc[dg], 1);
        order[lb[dg] + off2] = node;
    }
}

// ---------------------------------------------------------------- weight f32 -> hi/lo bf16
struct WSrc {
    const float* s[7];
    int off[8];
};
__global__ void k_cvt_w(WSrc ws, ushort_t* __restrict__ hi, ushort_t* __restrict__ lo) {
    int gid = blockIdx.x * 256 + threadIdx.x;
    int stride = gridDim.x * 256;
#pragma unroll
    for (int mi = 0; mi < 7; mi++) {
        int n = ws.off[mi + 1] - ws.off[mi];
        const float* s = ws.s[mi];
        ushort_t* h = hi + ws.off[mi];
        ushort_t* l = lo + ws.off[mi];
        for (int i = gid; i < n; i += stride) {
            float f = s[i];
            ushort_t hb = f2bf(f);
            h[i] = hb;
            l[i] = f2bf(f - bf2f(hb));
        }
    }
}

// ---------------------------------------------------------------- projection via MFMA
// One block per (64-row tile, L/R half). A fragments fully preloaded for MLP.
template <int K>
__global__ void k_gemm_dual_mfma(const ushort_t* __restrict__ xa,
                                 const ushort_t* __restrict__ wlh, const ushort_t* __restrict__ wll,
                                 const ushort_t* __restrict__ wrh, const ushort_t* __restrict__ wrl,
                                 const float* __restrict__ bl, const float* __restrict__ br,
                                 ushort_t* __restrict__ xl, ushort_t* __restrict__ xr) {
    int tid = threadIdx.x;
    int wv = tid >> 6, lane = tid & 63;
    bool rhalf = blockIdx.x >= GEMMB;
    int blk = rhalf ? blockIdx.x - GEMMB : blockIdx.x;
    int m0 = blk * 64 + wv * 16;
    if (m0 >= N_NODES) return;
    int arow = min(m0 + (lane & 15), N_NODES - 1);
    int koff = (lane >> 4) * 8;
    int wrow = lane & 15;
    const ushort_t* bh  = rhalf ? wrh : wlh;
    const ushort_t* blo = rhalf ? wrl : wll;
    const float* bias   = rhalf ? br : bl;
    ushort_t* outp      = rhalf ? xr : xl;

    // preload ALL A fragments (issues K/32 16B loads before any dependency)
    short8v afrag[K / 32];
#pragma unroll
    for (int kk = 0; kk < K / 32; kk++)
        afrag[kk] = *reinterpret_cast<const short8v*>(xa + (size_t)arow * K + kk * 32 + koff);

    float4v acc[4];
#pragma unroll
    for (int f = 0; f < 4; f++) acc[f] = (float4v)(0.f);

#pragma unroll
    for (int kk = 0; kk < K / 32; kk++) {
#pragma unroll
        for (int f = 0; f < 4; f++) {
            size_t boff = (size_t)(f * 16 + wrow) * K + kk * 32 + koff;
            short8v bfh = *reinterpret_cast<const short8v*>(bh + boff);
            short8v bfl = *reinterpret_cast<const short8v*>(blo + boff);
            acc[f] = __builtin_amdgcn_mfma_f32_16x16x32_bf16(afrag[kk], bfh, acc[f], 0, 0, 0);
            acc[f] = __builtin_amdgcn_mfma_f32_16x16x32_bf16(afrag[kk], bfl, acc[f], 0, 0, 0);
        }
    }

    int r0 = m0 + (lane >> 4) * 4;
#pragma unroll
    for (int f = 0; f < 4; f++) {
        int col = f * 16 + (lane & 15);
        float bv = bias[col];
#pragma unroll
        for (int j = 0; j < 4; j++) {
            int row = r0 + j;
            if (row < N_NODES) outp[(size_t)row * 64 + col] = f2bf(acc[f][j] + bv);
        }
    }
}

// ---------------------------------------------------------------- fused: h = relu(concat@W.T+b) -> global_add_pool
__global__ void k_gemm_h_pool(const ushort_t* __restrict__ x1, const ushort_t* __restrict__ x2,
                              const ushort_t* __restrict__ x3,
                              const ushort_t* __restrict__ whi, const ushort_t* __restrict__ wlo,
                              const float* __restrict__ b, const int* __restrict__ batch,
                              float* __restrict__ g) {
    __shared__ float ht[64][65];
    int tid = threadIdx.x;
    int wv = tid >> 6, lane = tid & 63;
    int m0 = blockIdx.x * 64 + wv * 16;
    bool wactive = m0 < N_NODES;

    if (wactive) {
        int arow = min(m0 + (lane & 15), N_NODES - 1);
        int koff = (lane >> 4) * 8;
        int wrow = lane & 15;
        float4v acc[4];
#pragma unroll
        for (int f = 0; f < 4; f++) acc[f] = (float4v)(0.f);
#pragma unroll
        for (int ks = 0; ks < 6; ks++) {
            int k0 = ks * 32;
            const ushort_t* srcp = (ks < 2) ? x1 : (ks < 4 ? x2 : x3);
            int kc = k0 & 63;
            short8v afrag = *reinterpret_cast<const short8v*>(srcp + (size_t)arow * 64 + kc + koff);
#pragma unroll
            for (int f = 0; f < 4; f++) {
                size_t boff = (size_t)(f * 16 + wrow) * 192 + k0 + koff;
                short8v bfh = *reinterpret_cast<const short8v*>(whi + boff);
                short8v bfl = *reinterpret_cast<const short8v*>(wlo + boff);
                acc[f] = __builtin_amdgcn_mfma_f32_16x16x32_bf16(afrag, bfh, acc[f], 0, 0, 0);
                acc[f] = __builtin_amdgcn_mfma_f32_16x16x32_bf16(afrag, bfl, acc[f], 0, 0, 0);
            }
        }
        int r0 = wv * 16 + (lane >> 4) * 4;
#pragma unroll
        for (int f = 0; f < 4; f++) {
            int col = f * 16 + (lane & 15);
            float bias = b[col];
#pragma unroll
            for (int j = 0; j < 4; j++) {
                float o = acc[f][j] + bias;
                ht[r0 + j][col] = o > 0.f ? o : 0.f;
            }
        }
    }
    __syncthreads();

    int c = tid & 63, rr = tid >> 6;
    int blkbase = blockIdx.x * 64;
    float acc = 0.f;
    int cur = -1;
    for (int r = rr; r < 64; r += 4) {
        int node = blkbase + r;
        if (node >= N_NODES) break;
        int bb = batch[node];
        if (bb != cur) {
            if (cur >= 0) atomicAdd(&g[cur * 64 + c], acc);
            cur = bb;
            acc = 0.f;
        }
        acc += ht[r][c];
    }
    if (cur >= 0) atomicAdd(&g[cur * 64 + c], acc);
}

// ---------------------------------------------------------------- GATv2 aggregate
// 4 nodes/wave (16 lanes, 4ch/lane), degree-ordered; 8-edge unrolled online softmax (log2 domain)
__global__ void k_gat(const ushort_t* __restrict__ xl, const ushort_t* __restrict__ xr,
                      const int* __restrict__ rowptr, const int* __restrict__ csr_src,
                      const int* __restrict__ order,
                      const float* __restrict__ att, const float* __restrict__ bo,
                      ushort_t* __restrict__ xout) {
    int tid = threadIdx.x;
    int wv = tid >> 6, lane = tid & 63;
    int gl = lane & 15;
    int slot = blockIdx.x * 16 + wv * 4 + (lane >> 4);
    if (slot >= N_NODES) return;
    int node = order[slot];
    const float LOG2E = 1.44269504f;
    int c0 = gl * 4;
    float4 a4 = *reinterpret_cast<const float4*>(att + c0);
    float at0 = a4.x * LOG2E, at1 = a4.y * LOG2E, at2 = a4.z * LOG2E, at3 = a4.w * LOG2E;
    size_t nb = (size_t)node * 64 + c0;
    ushort4 qr = *reinterpret_cast<const ushort4*>(xr + nb);
    ushort4 ql = *reinterpret_cast<const ushort4*>(xl + nb);
    float xr0 = bf2f(qr.x), xr1 = bf2f(qr.y), xr2 = bf2f(qr.z), xr3 = bf2f(qr.w);
    float l0 = bf2f(ql.x), l1 = bf2f(ql.y), l2 = bf2f(ql.z), l3 = bf2f(ql.w);

    auto grd = [](float p) {
        p += __shfl_xor(p, 1);
        p += __shfl_xor(p, 2);
        p += __shfl_xor(p, 4);
        p += __shfl_xor(p, 8);
        return p;
    };
    auto score4 = [&](float v0, float v1, float v2, float v3) {
        float s0 = v0 + xr0, s1 = v1 + xr1, s2 = v2 + xr2, s3 = v3 + xr3;
        float t0 = fmaxf(s0, LRELU_SLOPE * s0);
        float t1 = fmaxf(s1, LRELU_SLOPE * s1);
        float t2 = fmaxf(s2, LRELU_SLOPE * s2);
        float t3 = fmaxf(s3, LRELU_SLOPE * s3);
        return ((t0 * at0 + t1 * at1) + (t2 * at2 + t3 * at3));
    };

    int beg = rowptr[node], end = rowptr[node + 1];
    int deg = end - beg;
    int lim = end - 1;

    float m = grd(score4(l0, l1, l2, l3));
    float ssum = 1.f;
    float a0 = l0, a1 = l1, a2 = l2, a3 = l3;

    for (int j = 0; j < deg; j += 8) {
        int base = beg + j;
        int i0 = base;
        int i1 = min(base + 1, lim), i2 = min(base + 2, lim), i3 = min(base + 3, lim);
        int i4 = min(base + 4, lim), i5 = min(base + 5, lim);
        int i6 = min(base + 6, lim), i7 = min(base + 7, lim);
        int s0 = csr_src[i0], s1 = csr_src[i1], s2 = csr_src[i2], s3 = csr_src[i3];
        int s4 = csr_src[i4], s5 = csr_src[i5], s6 = csr_src[i6], s7 = csr_src[i7];
        ushort4 q0 = *reinterpret_cast<const ushort4*>(xl + (size_t)s0 * 64 + c0);
        ushort4 q1 = *reinterpret_cast<const ushort4*>(xl + (size_t)s1 * 64 + c0);
        ushort4 q2 = *reinterpret_cast<const ushort4*>(xl + (size_t)s2 * 64 + c0);
        ushort4 q3 = *reinterpret_cast<const ushort4*>(xl + (size_t)s3 * 64 + c0);
        ushort4 q4 = *reinterpret_cast<const ushort4*>(xl + (size_t)s4 * 64 + c0);
        ushort4 q5 = *reinterpret_cast<const ushort4*>(xl + (size_t)s5 * 64 + c0);
        ushort4 q6 = *reinterpret_cast<const ushort4*>(xl + (size_t)s6 * 64 + c0);
        ushort4 q7 = *reinterpret_cast<const ushort4*>(xl + (size_t)s7 * 64 + c0);
        float v00 = bf2f(q0.x), v01 = bf2f(q0.y), v02 = bf2f(q0.z), v03 = bf2f(q0.w);
        float v10 = bf2f(q1.x), v11 = bf2f(q1.y), v12 = bf2f(q1.z), v13 = bf2f(q1.w);
        float v20 = bf2f(q2.x), v21 = bf2f(q2.y), v22 = bf2f(q2.z), v23 = bf2f(q2.w);
        float v30 = bf2f(q3.x), v31 = bf2f(q3.y), v32 = bf2f(q3.z), v33 = bf2f(q3.w);
        float v40 = bf2f(q4.x), v41 = bf2f(q4.y), v42 = bf2f(q4.z), v43 = bf2f(q4.w);
        float v50 = bf2f(q5.x), v51 = bf2f(q5.y), v52 = bf2f(q5.z), v53 = bf2f(q5.w);
        float v60 = bf2f(q6.x), v61 = bf2f(q6.y), v62 = bf2f(q6.z), v63 = bf2f(q6.w);
        float v70 = bf2f(q7.x), v71 = bf2f(q7.y), v72 = bf2f(q7.z), v73 = bf2f(q7.w);
        float e0 = grd(score4(v00, v01, v02, v03));
        float e1 = grd(score4(v10, v11, v12, v13));
        float e2 = grd(score4(v20, v21, v22, v23));
        float e3 = grd(score4(v30, v31, v32, v33));
        float e4 = grd(score4(v40, v41, v42, v43));
        float e5 = grd(score4(v50, v51, v52, v53));
        float e6 = grd(score4(v60, v61, v62, v63));
        float e7 = grd(score4(v70, v71, v72, v73));
        int rem = deg - j;
        if (rem < 8) {
            e1 = (rem > 1) ? e1 : -1e30f;
            e2 = (rem > 2) ? e2 : -1e30f;
            e3 = (rem > 3) ? e3 : -1e30f;
            e4 = (rem > 4) ? e4 : -1e30f;
            e5 = (rem > 5) ? e5 : -1e30f;
            e6 = (rem > 6) ? e6 : -1e30f;
            e7 = (rem > 7) ? e7 : -1e30f;
        }
        float mx = fmaxf(fmaxf(fmaxf(e0, e1), fmaxf(e2, e3)),
                         fmaxf(fmaxf(e4, e5), fmaxf(e6, e7)));
        float mn = fmaxf(m, mx);
        float sc = fast_exp2(m - mn);
        float w0 = fast_exp2(e0 - mn), w1 = fast_exp2(e1 - mn);
        float w2 = fast_exp2(e2 - mn), w3 = fast_exp2(e3 - mn);
        float w4 = fast_exp2(e4 - mn), w5 = fast_exp2(e5 - mn);
        float w6 = fast_exp2(e6 - mn), w7 = fast_exp2(e7 - mn);
        ssum = ssum * sc + (((w0 + w1) + (w2 + w3)) + ((w4 + w5) + (w6 + w7)));
        a0 = a0 * sc + (((w0 * v00 + w1 * v10) + (w2 * v20 + w3 * v30)) +
                        ((w4 * v40 + w5 * v50) + (w6 * v60 + w7 * v70)));
        a1 = a1 * sc + (((w0 * v01 + w1 * v11) + (w2 * v21 + w3 * v31)) +
                        ((w4 * v41 + w5 * v51) + (w6 * v61 + w7 * v71)));
        a2 = a2 * sc + (((w0 * v02 + w1 * v12) + (w2 * v22 + w3 * v32)) +
                        ((w4 * v42 + w5 * v52) + (w6 * v62 + w7 * v72)));
        a3 = a3 * sc + (((w0 * v03 + w1 * v13) + (w2 * v23 + w3 * v33)) +
                        ((w4 * v43 + w5 * v53) + (w6 * v63 + w7 * v73)));
        m = mn;
    }

    float rs = 1.f / (ssum + 1e-16f);
    float4 b4 = *reinterpret_cast<const float4*>(bo + c0);
    float o0 = fmaxf(a0 * rs + b4.x, 0.f);
    float o1 = fmaxf(a1 * rs + b4.y, 0.f);
    float o2 = fmaxf(a2 * rs + b4.z, 0.f);
    float o3 = fmaxf(a3 * rs + b4.w, 0.f);
    ushort4 oq;
    oq.x = f2bf(o0); oq.y = f2bf(o1); oq.z = f2bf(o2); oq.w = f2bf(o3);
    *reinterpret_cast<ushort4*>(xout + nb) = oq;
}

// ---------------------------------------------------------------- head
__global__ void k_head(const float* __restrict__ g, const float* __restrict__ pw,
                       const float* __restrict__ pb, const float* __restrict__ cw,
                       const float* __restrict__ cb, float* __restrict__ out) {
    int gb = blockIdx.x;
    int c = threadIdx.x;
    const float* gr = g + gb * 64;
    float a = pb[c];
    const float* pwr = pw + c * 64;
#pragma unroll
    for (int k = 0; k < 64; k++) a += gr[k] * pwr[k];
    a = a > 0.f ? a : 0.f;
    float o0 = wave_sum(a * cw[c]);
    float o1 = wave_sum(a * cw[64 + c]);
    if (c == 0) {
        out[gb * 2 + 0] = o0 + cb[0];
        out[gb * 2 + 1] = o1 + cb[1];
    }
}

// ---------------------------------------------------------------- launcher
extern "C" void kernel_launch(void* const* d_in, const int* in_sizes, int n_in,
                              void* d_out, int out_size, void* d_ws, size_t ws_size,
                              hipStream_t stream) {
    const float* x    = (const float*)d_in[0];
    const int*   ei   = (const int*)d_in[1];
    const int*   bidx = (const int*)d_in[2];
    const float* wl1 = (const float*)d_in[3],  *bl1 = (const float*)d_in[4];
    const float* wr1 = (const float*)d_in[5],  *br1 = (const float*)d_in[6];
    const float* att1 = (const float*)d_in[7], *bo1 = (const float*)d_in[8];
    const float* wl2 = (const float*)d_in[9],  *bl2 = (const float*)d_in[10];
    const float* wr2 = (const float*)d_in[11], *br2 = (const float*)d_in[12];
    const float* att2 = (const float*)d_in[13], *bo2 = (const float*)d_in[14];
    const float* wl3 = (const float*)d_in[15], *bl3 = (const float*)d_in[16];
    const float* wr3 = (const float*)d_in[17], *br3 = (const float*)d_in[18];
    const float* att3 = (const float*)d_in[19], *bo3 = (const float*)d_in[20];
    const float* lw = (const float*)d_in[21], *lb = (const float*)d_in[22];
    const float* pw = (const float*)d_in[23], *pb = (const float*)d_in[24];
    const float* cw = (const float*)d_in[25], *cb = (const float*)d_in[26];
    float* out = (float*)d_out;

    char* wsb = (char*)d_ws;
    size_t off = 0;
    auto alloc = [&](size_t bytes) {
        void* p = wsb + off;
        off = (off + bytes + 255) & ~(size_t)255;
        return p;
    };
    int* cnt      = (int*)alloc((size_t)N_NODES * 4);
    int* rowptr   = (int*)alloc((size_t)(N_NODES + 1) * 4);
    int* bcnt     = (int*)alloc((size_t)(NBUCK + NDBIN) * 4);  // bcnt + dhist, one memset
    int* dhist    = bcnt + NBUCK;
    int* bbase    = (int*)alloc((size_t)NBUCK * 4);
    int* dcur     = (int*)alloc((size_t)NDBIN * 4);
    int* order    = (int*)alloc((size_t)N_NODES * 4);
    int2* stage   = (int2*)alloc((size_t)NBUCK * BCAP * 8);
    int* csr_src  = (int*)alloc((size_t)N_EDGES * 4);
    const int woff[8] = {0, 8192, 16384, 20480, 24576, 28672, 32768, 45056};
    ushort_t* whi = (ushort_t*)alloc((size_t)45056 * 2);
    ushort_t* wlo = (ushort_t*)alloc((size_t)45056 * 2);
    ushort_t* xbf  = (ushort_t*)alloc((size_t)N_NODES * FDIM * 2);
    ushort_t* xl   = (ushort_t*)alloc((size_t)N_NODES * 64 * 2);
    ushort_t* xrr  = (ushort_t*)alloc((size_t)N_NODES * 64 * 2);
    ushort_t* x1b  = (ushort_t*)alloc((size_t)N_NODES * 64 * 2);
    ushort_t* x2b  = (ushort_t*)alloc((size_t)N_NODES * 64 * 2);
    ushort_t* x3b  = (ushort_t*)alloc((size_t)N_NODES * 64 * 2);
    float* g      = (float*)alloc((size_t)NGRAPH * 64 * 4);
    (void)ws_size; (void)in_sizes; (void)n_in; (void)out_size;

    const int* srcp = ei;
    const int* dstp = ei + N_EDGES;

    hipMemsetAsync(bcnt, 0, (size_t)(NBUCK + NDBIN) * 4, stream);
    hipMemsetAsync(g, 0, (size_t)NGRAPH * 64 * 4, stream);

    k_bucket<<<ABLK, 256, 0, stream>>>(srcp, dstp, bcnt, stage);
    k_bscan<<<1, 256, 0, stream>>>(bcnt, bbase);
    k_csr<<<NBUCK, 256, 0, stream>>>(bcnt, bbase, stage, rowptr, cnt, dhist, csr_src);
    k_scan2d<<<1, 64, 0, stream>>>(dhist, dcur);
    k_dscatter<<<NBUCK, 256, 0, stream>>>(cnt, dcur, order);

    WSrc ws;
    ws.s[0] = wl1; ws.s[1] = wr1; ws.s[2] = wl2; ws.s[3] = wr2;
    ws.s[4] = wl3; ws.s[5] = wr3; ws.s[6] = lw;
    for (int i = 0; i < 8; i++) ws.off[i] = woff[i];
    k_cvt_w<<<64, 256, 0, stream>>>(ws, whi, wlo);
    k_cvt_x<<<(N_NODES * FDIM / 8 + 255) / 256, 256, 0, stream>>>(x, xbf);

    int gatBlocks = (N_NODES + 15) / 16;

    // layer 1 (K=128, A = xbf)
    k_gemm_dual_mfma<128><<<2 * GEMMB, 256, 0, stream>>>(
        xbf, whi + woff[0], wlo + woff[0], whi + woff[1], wlo + woff[1], bl1, br1, xl, xrr);
    k_gat<<<gatBlocks, 256, 0, stream>>>(xl, xrr, rowptr, csr_src, order, att1, bo1, x1b);
    // layer 2
    k_gemm_dual_mfma<64><<<2 * GEMMB, 256, 0, stream>>>(
        x1b, whi + woff[2], wlo + woff[2], whi + woff[3], wlo + woff[3], bl2, br2, xl, xrr);
    k_gat<<<gatBlocks, 256, 0, stream>>>(xl, xrr, rowptr, csr_src, order, att2, bo2, x2b);
    // layer 3
    k_gemm_dual_mfma<64><<<2 * GEMMB, 256, 0, stream>>>(
        x2b, whi + woff[4], wlo + woff[4], whi + woff[5], wlo + woff[5], bl3, br3, xl, xrr);
    k_gat<<<gatBlocks, 256, 0, stream>>>(xl, xrr, rowptr, csr_src, order, att3, bo3, x3b);

    // fused head GEMM + pool, then classifier
    k_gemm_h_pool<<<GEMMB, 256, 0, stream>>>(x1b, x2b, x3b, whi + woff[6], wlo + woff[6],
                                             lb, bidx, g);
    k_head<<<NGRAPH, 64, 0, stream>>>(g, pw, pb, cw, cb, out);
}